// Round 1
// baseline (13276.451 us; speedup 1.0000x reference)
//
#include <hip/hip_runtime.h>
#include <math.h>

// ChainedGP: sparse-GP ELBO, N=16384, M=2048, D=8, fp32.
// Workspace requirement: ~202 MB (Kuu/Lk 16MB + Linv 16MB + Wf/Wg 32MB + T^T 134MB + small).
#define NN 16384
#define MM 2048
#define DD 8
#define BB 64
#define NB 32   // MM/BB

constexpr float KVAR    = 1.0f;
constexpr float GAMMA   = 2.0f;      // 0.5/LS^2, LS=0.5
constexpr float KJITTER = 1e-6f;
constexpr float HLOG2PI = 0.91893853320467274178f;

// ---- workspace layout (float offsets) ----
#define OFF_KUU  ((size_t)0)
#define OFF_LINV ((size_t)4*1024*1024)
#define OFF_WF   ((size_t)8*1024*1024)
#define OFF_WG   ((size_t)12*1024*1024)
#define OFF_TT   ((size_t)16*1024*1024)            // col-major [MM][NN]
#define OFF_AF   (OFF_TT + (size_t)NN*MM)          // 48M
#define OFF_AG   (OFF_AF + MM)
#define OFF_T2   (OFF_AG + MM)
#define OFF_LF   (OFF_T2 + NN)
#define OFF_LG   (OFF_LF + NN)
#define OFF_VFQ  (OFF_LG + NN)
#define OFF_VGQ  (OFF_VFQ + NN)
#define OFF_SCAL (OFF_VGQ + NN)                    // 16 scalars

__device__ __forceinline__ float block_reduce(float v, float* scratch){
  int lane = threadIdx.x & 63;
  int w    = threadIdx.x >> 6;
  #pragma unroll
  for (int off=32; off; off>>=1) v += __shfl_down(v, off, 64);
  __syncthreads();                 // protect scratch reuse across calls
  if (lane==0) scratch[w] = v;
  __syncthreads();
  float r = 0.f;
  if (threadIdx.x < 4) r = scratch[threadIdx.x];
  if (w==0){ r += __shfl_down(r, 2, 64); r += __shfl_down(r, 1, 64); }
  return r;                        // valid at thread 0
}

// ---------- Kuu = rbf(z,z) + jitter I ----------
__global__ __launch_bounds__(256) void kuu_kernel(const float* __restrict__ z, float* __restrict__ kuu){
  int idx = blockIdx.x*256 + threadIdx.x;
  int i = idx >> 11, j = idx & 2047;
  float d2 = 0.f;
  #pragma unroll
  for (int d=0; d<DD; ++d){ float df = z[i*DD+d] - z[j*DD+d]; d2 += df*df; }
  float v = KVAR * __expf(-GAMMA*d2);
  if (i==j) v += KJITTER;
  kuu[(size_t)i*MM + j] = v;
}

// ---------- Cholesky: 64x64 diagonal block, single wave ----------
__global__ __launch_bounds__(64) void chol_diag(float* __restrict__ a, int kb){
  __shared__ float s[BB][BB+1];
  int lane = threadIdx.x;
  int base = kb*BB;
  for (int c=0;c<BB;++c) s[lane][c] = a[(size_t)(base+lane)*MM + base + c];
  __syncthreads();
  for (int j=0;j<BB;++j){
    if (lane==j) s[j][j] = sqrtf(fmaxf(s[j][j], 1e-20f));
    __syncthreads();
    if (lane>j) s[lane][j] /= s[j][j];
    __syncthreads();
    for (int c=j+1;c<=lane;++c) s[lane][c] -= s[lane][j]*s[c][j];
    __syncthreads();
  }
  for (int c=0;c<BB;++c) a[(size_t)(base+lane)*MM + base + c] = (c<=lane) ? s[lane][c] : 0.f;
}

// ---------- Cholesky: panel TRSM (row-wise x * Lkk^T = a) ----------
__global__ __launch_bounds__(128) void trsm_panel(float* __restrict__ a, int kb){
  __shared__ float lkk[BB][BB+1];
  __shared__ float xs[128][BB+1];
  int t = threadIdx.x;
  int base = kb*BB;
  for (int p=t;p<BB*BB;p+=128){ int i=p>>6, c=p&63; lkk[i][c] = a[(size_t)(base+i)*MM + base + c]; }
  int r = base + BB + blockIdx.x*128 + t;
  bool act = r < MM;
  size_t rowoff = act ? ((size_t)r*MM + base) : 0;
  for (int c=0;c<BB;++c) xs[t][c] = act ? a[rowoff + c] : 0.f;
  __syncthreads();
  for (int j=0;j<BB;++j){
    float s = xs[t][j];
    for (int i=0;i<j;++i) s -= xs[t][i]*lkk[j][i];
    xs[t][j] = s / lkk[j][j];
  }
  if (act) for (int c=0;c<BB;++c) a[rowoff + c] = xs[t][c];
}

// ---------- Cholesky: trailing SYRK (lower blocks only) ----------
__global__ __launch_bounds__(256) void syrk_update(float* __restrict__ a, int kb){
  int bi = kb + 1 + blockIdx.y;
  int bc = kb + 1 + blockIdx.x;
  if (bc > bi) return;
  __shared__ float P[BB][BB+1], Q[BB][BB+1];
  int t = threadIdx.x, tx = t&15, ty = t>>4;
  for (int p=t;p<BB*BB;p+=256){
    int i=p>>6, c=p&63;
    P[i][c] = a[(size_t)(bi*BB+i)*MM + kb*BB + c];
    Q[i][c] = a[(size_t)(bc*BB+i)*MM + kb*BB + c];
  }
  __syncthreads();
  float acc[4][4] = {};
  for (int k=0;k<BB;++k){
    float pr[4], qc[4];
    #pragma unroll
    for (int u=0;u<4;++u){ pr[u]=P[ty*4+u][k]; qc[u]=Q[tx*4+u][k]; }
    #pragma unroll
    for (int u=0;u<4;++u)
      #pragma unroll
      for (int v=0;v<4;++v) acc[u][v] += pr[u]*qc[v];
  }
  #pragma unroll
  for (int u=0;u<4;++u)
    #pragma unroll
    for (int v=0;v<4;++v)
      a[(size_t)(bi*BB+ty*4+u)*MM + bc*BB + tx*4+v] -= acc[u][v];
}

// ---------- invert diagonal blocks of Lk (zeros upper) ----------
__global__ __launch_bounds__(64) void inv_diag(const float* __restrict__ lk, float* __restrict__ linv){
  __shared__ float L[BB][BB+1];
  __shared__ float X[BB][BB+1];
  int lane = threadIdx.x;     // column index
  int b = blockIdx.x;
  for (int c=0;c<BB;++c) L[lane][c] = lk[(size_t)(b*BB+lane)*MM + b*BB + c];
  __syncthreads();
  for (int j=0;j<BB;++j){
    float s = (j==lane) ? 1.f : 0.f;
    for (int k=lane;k<j;++k) s -= L[j][k]*X[k][lane];
    X[j][lane] = (j>=lane) ? s / L[j][j] : 0.f;
  }
  __syncthreads();
  for (int j=0;j<BB;++j) linv[(size_t)(b*BB+j)*MM + b*BB + lane] = X[j][lane];
}

// ---------- off-diagonal inversion, subdiagonal distance d ----------
__global__ __launch_bounds__(256) void inv_off(const float* __restrict__ lk, float* __restrict__ linv, int d){
  int bj = blockIdx.x;
  int bi = bj + d;
  __shared__ float As[BB][BB+1], Bs[BB][BB+1];
  int t=threadIdx.x, tx=t&15, ty=t>>4;
  float acc[4][4] = {};
  for (int bk=bj; bk<bi; ++bk){
    __syncthreads();
    for (int p=t;p<BB*BB;p+=256){
      int i=p>>6, c=p&63;
      As[i][c] = lk[(size_t)(bi*BB+i)*MM + bk*BB + c];
      Bs[i][c] = linv[(size_t)(bk*BB+i)*MM + bj*BB + c];
    }
    __syncthreads();
    for (int k=0;k<BB;++k){
      float ar[4], bc4[4];
      #pragma unroll
      for (int u=0;u<4;++u){ ar[u]=As[ty*4+u][k]; bc4[u]=Bs[k][tx*4+u]; }
      #pragma unroll
      for (int u=0;u<4;++u)
        #pragma unroll
        for (int v=0;v<4;++v) acc[u][v] += ar[u]*bc4[v];
    }
  }
  __syncthreads();
  #pragma unroll
  for (int u=0;u<4;++u)
    #pragma unroll
    for (int v=0;v<4;++v) As[ty*4+u][tx*4+v] = acc[u][v];
  for (int p=t;p<BB*BB;p+=256){
    int i=p>>6, c=p&63;
    Bs[i][c] = linv[(size_t)(bi*BB+i)*MM + bi*BB + c];
  }
  __syncthreads();
  float out[4][4] = {};
  for (int k=0;k<BB;++k){
    float xr[4], tc[4];
    #pragma unroll
    for (int u=0;u<4;++u){ xr[u]=Bs[ty*4+u][k]; tc[u]=As[k][tx*4+u]; }
    #pragma unroll
    for (int u=0;u<4;++u)
      #pragma unroll
      for (int v=0;v<4;++v) out[u][v] += xr[u]*tc[v];
  }
  #pragma unroll
  for (int u=0;u<4;++u)
    #pragma unroll
    for (int v=0;v<4;++v)
      linv[(size_t)(bi*BB+ty*4+u)*MM + bj*BB + tx*4+v] = -out[u][v];
}

// ---------- W = Linv @ tril(qL)  (lower-tri result; W buffers pre-zeroed) ----------
__global__ __launch_bounds__(256) void w_kernel(const float* __restrict__ linv,
    const float* __restrict__ qlf, const float* __restrict__ qlg,
    float* __restrict__ wf, float* __restrict__ wg){
  int bj = blockIdx.x, bi = blockIdx.y;
  if (bi < bj) return;
  const float* ql = blockIdx.z ? qlg : qlf;
  float* w        = blockIdx.z ? wg  : wf;
  __shared__ float As[BB][BB+1], Bs[BB][BB+1];
  int t=threadIdx.x, tx=t&15, ty=t>>4;
  float acc[4][4] = {};
  for (int bk=bj; bk<=bi; ++bk){
    __syncthreads();
    for (int p=t;p<BB*BB;p+=256){
      int i=p>>6, c=p&63;
      As[i][c] = linv[(size_t)(bi*BB+i)*MM + bk*BB + c];
      float qv = ql[(size_t)(bk*BB+i)*MM + bj*BB + c];
      if (bk==bj && i<c) qv = 0.f;     // tril (diag kept)
      Bs[i][c] = qv;
    }
    __syncthreads();
    for (int k=0;k<BB;++k){
      float ar[4], bc4[4];
      #pragma unroll
      for (int u=0;u<4;++u){ ar[u]=As[ty*4+u][k]; bc4[u]=Bs[k][tx*4+u]; }
      #pragma unroll
      for (int u=0;u<4;++u)
        #pragma unroll
        for (int v=0;v<4;++v) acc[u][v] += ar[u]*bc4[v];
    }
  }
  #pragma unroll
  for (int u=0;u<4;++u)
    #pragma unroll
    for (int v=0;v<4;++v)
      w[(size_t)(bi*BB+ty*4+u)*MM + bj*BB + tx*4+v] = acc[u][v];
}

// ---------- alpha = Linv @ qm ----------
__global__ __launch_bounds__(256) void alpha_kernel(const float* __restrict__ linv,
    const float* __restrict__ qmf, const float* __restrict__ qmg,
    float* __restrict__ af, float* __restrict__ ag){
  __shared__ float scratch[4];
  int r = blockIdx.x;
  const float* qm = blockIdx.y ? qmg : qmf;
  float* a        = blockIdx.y ? ag  : af;
  float s = 0.f;
  for (int c=threadIdx.x;c<=r;c+=256) s += linv[(size_t)r*MM + c]*qm[c];
  s = block_reduce(s, scratch);
  if (threadIdx.x==0) a[r] = s;
}

// ---------- small reductions: logdets + ||alpha||^2 ----------
__global__ __launch_bounds__(256) void red_small(const float* __restrict__ lk,
    const float* __restrict__ qlf, const float* __restrict__ qlg,
    const float* __restrict__ af, const float* __restrict__ ag,
    float* __restrict__ scal){
  __shared__ float scratch[4];
  float ldk=0, ldf=0, ldg=0, a2f=0, a2g=0;
  for (int i=threadIdx.x;i<MM;i+=256){
    ldk += __logf(lk[(size_t)i*MM+i]);
    ldf += __logf(fabsf(qlf[(size_t)i*MM+i]));
    ldg += __logf(fabsf(qlg[(size_t)i*MM+i]));
    float v = af[i]; a2f += v*v;
    v = ag[i];       a2g += v*v;
  }
  float r;
  r = block_reduce(ldk, scratch); if (threadIdx.x==0) scal[0] = 2.f*r;
  r = block_reduce(ldf, scratch); if (threadIdx.x==0) scal[1] = 2.f*r;
  r = block_reduce(ldg, scratch); if (threadIdx.x==0) scal[2] = 2.f*r;
  r = block_reduce(a2f, scratch); if (threadIdx.x==0) scal[3] = r;
  r = block_reduce(a2g, scratch); if (threadIdx.x==0) scal[4] = r;
}

// ---------- ||W_f||^2, ||W_g||^2 ----------
__global__ __launch_bounds__(256) void redw_kernel(const float* __restrict__ wf,
    const float* __restrict__ wg, float* __restrict__ scal){
  __shared__ float scratch[4];
  size_t start  = (size_t)blockIdx.x*256 + threadIdx.x;
  size_t stride = (size_t)gridDim.x*256;
  float sf=0, sg=0;
  for (size_t p=start;p<(size_t)MM*MM;p+=stride){
    float v=wf[p]; sf += v*v;
    v=wg[p];       sg += v*v;
  }
  float r = block_reduce(sf, scratch);
  if (threadIdx.x==0) atomicAdd(&scal[5], r);
  r = block_reduce(sg, scratch);
  if (threadIdx.x==0) atomicAdd(&scal[6], r);
}

// ---------- KL terms into out ----------
__global__ void kl_kernel(const float* __restrict__ scal, float* __restrict__ out){
  float klf = 0.5f*(scal[5] + scal[3] - (float)MM + scal[0] - scal[1]);
  float klg = 0.5f*(scal[6] + scal[4] - (float)MM + scal[0] - scal[2]);
  out[0] += klf + klg;
}

// ---------- T^T = Kfu @ Linv^T (Kfu computed on the fly), col-major out ----------
__global__ __launch_bounds__(256) void tt_kernel(const float* __restrict__ x,
    const float* __restrict__ z, const float* __restrict__ linv, float* __restrict__ tt){
  __shared__ float xs[128][DD+1];
  __shared__ float kfuT[BB][132];   // [zcol][xrow]
  __shared__ float lt[BB][68];      // [k][jcol] = Linv[jcol][k]
  int istrip = blockIdx.x, bj = blockIdx.y;
  int t = threadIdx.x, tx = t&15, ty = t>>4;
  for (int p=t;p<128*DD;p+=256){ int r=p>>3, d=p&7; xs[r][d] = x[(size_t)(istrip*128+r)*DD + d]; }
  float acc[8][4] = {};
  for (int bk=0; bk<=bj; ++bk){         // Linv^T block (bk,bj) nonzero iff bk<=bj
    __syncthreads();
    for (int p=t;p<BB*128;p+=256){
      int c=p>>7, r=p&127;
      float d2=0.f;
      #pragma unroll
      for (int dd=0;dd<DD;++dd){ float df = xs[r][dd] - z[(size_t)(bk*BB+c)*DD + dd]; d2 += df*df; }
      kfuT[c][r] = KVAR * __expf(-GAMMA*d2);
    }
    for (int p=t;p<BB*BB;p+=256){
      int j=p>>6, k=p&63;
      lt[k][j] = linv[(size_t)(bj*BB+j)*MM + bk*BB + k];
    }
    __syncthreads();
    for (int k=0;k<BB;++k){
      float ar[8], bc4[4];
      *(float4*)&ar[0]  = *(const float4*)&kfuT[k][ty*8];
      *(float4*)&ar[4]  = *(const float4*)&kfuT[k][ty*8+4];
      *(float4*)&bc4[0] = *(const float4*)&lt[k][tx*4];
      #pragma unroll
      for (int u=0;u<8;++u)
        #pragma unroll
        for (int v=0;v<4;++v) acc[u][v] += ar[u]*bc4[v];
    }
  }
  #pragma unroll
  for (int v=0;v<4;++v){
    int col = bj*BB + tx*4 + v;
    size_t b2 = (size_t)col*NN + istrip*128 + ty*8;
    float4 w0 = make_float4(acc[0][v],acc[1][v],acc[2][v],acc[3][v]);
    float4 w1 = make_float4(acc[4][v],acc[5][v],acc[6][v],acc[7][v]);
    *(float4*)&tt[b2]   = w0;
    *(float4*)&tt[b2+4] = w1;
  }
}

// ---------- per-row ||t||^2, t.alpha_f, t.alpha_g ----------
__global__ __launch_bounds__(256) void lin_kernel(const float* __restrict__ tt,
    const float* __restrict__ af, const float* __restrict__ ag,
    float* __restrict__ t2, float* __restrict__ lf, float* __restrict__ lg){
  int r  = blockIdx.x*256 + threadIdx.x;
  int c0 = blockIdx.y*(MM/8);
  float s2=0, sf=0, sg=0;
  for (int c=c0;c<c0+MM/8;++c){
    float v = tt[(size_t)c*NN + r];
    s2 += v*v; sf += v*af[c]; sg += v*ag[c];
  }
  atomicAdd(&t2[r], s2); atomicAdd(&lf[r], sf); atomicAdd(&lg[r], sg);
}

// ---------- U = T^T @ W for both GPs; accumulate row-sums of squares ----------
__global__ __launch_bounds__(256) void quad_kernel(const float* __restrict__ tt,
    const float* __restrict__ wf, const float* __restrict__ wg,
    float* __restrict__ vfq, float* __restrict__ vgq){
  __shared__ float tts[BB][BB+4];   // [k][r]
  __shared__ float wfs[BB][BB];     // [k][c]
  __shared__ float wgs[BB][BB];
  int istrip = blockIdx.x;          // NN/64
  int bj = blockIdx.y;
  int t = threadIdx.x, tx=t&15, ty=t>>4;
  float accf[4][4]={}, accg[4][4]={};
  for (int bk=bj; bk<NB; ++bk){     // W block (bk,bj) nonzero iff bk>=bj
    __syncthreads();
    for (int p=t;p<BB*(BB/4);p+=256){
      int k=p>>4, r4=p&15;
      float4 v = *(const float4*)&tt[(size_t)(bk*BB+k)*NN + istrip*BB + r4*4];
      *(float4*)&tts[k][r4*4] = v;
    }
    for (int p=t;p<BB*BB;p+=256){
      int k=p>>6, c=p&63;
      wfs[k][c] = wf[(size_t)(bk*BB+k)*MM + bj*BB + c];
      wgs[k][c] = wg[(size_t)(bk*BB+k)*MM + bj*BB + c];
    }
    __syncthreads();
    for (int k=0;k<BB;++k){
      float ar[4], bf4[4], bg4[4];
      *(float4*)&ar[0]  = *(const float4*)&tts[k][ty*4];
      *(float4*)&bf4[0] = *(const float4*)&wfs[k][tx*4];
      *(float4*)&bg4[0] = *(const float4*)&wgs[k][tx*4];
      #pragma unroll
      for (int u=0;u<4;++u)
        #pragma unroll
        for (int v=0;v<4;++v){ accf[u][v] += ar[u]*bf4[v]; accg[u][v] += ar[u]*bg4[v]; }
    }
  }
  float rf[4], rg[4];
  #pragma unroll
  for (int u=0;u<4;++u){
    rf[u] = accf[u][0]*accf[u][0] + accf[u][1]*accf[u][1] + accf[u][2]*accf[u][2] + accf[u][3]*accf[u][3];
    rg[u] = accg[u][0]*accg[u][0] + accg[u][1]*accg[u][1] + accg[u][2]*accg[u][2] + accg[u][3]*accg[u][3];
  }
  #pragma unroll
  for (int off=8;off;off>>=1){
    #pragma unroll
    for (int u=0;u<4;++u){ rf[u] += __shfl_down(rf[u], off, 64); rg[u] += __shfl_down(rg[u], off, 64); }
  }
  if (tx==0){
    int row = istrip*BB + ty*4;
    #pragma unroll
    for (int u=0;u<4;++u){ atomicAdd(&vfq[row+u], rf[u]); atomicAdd(&vgq[row+u], rg[u]); }
  }
}

// ---------- expectation term + reduce ----------
__global__ __launch_bounds__(256) void final_kernel(const float* __restrict__ y,
    const float* __restrict__ t2, const float* __restrict__ lf, const float* __restrict__ lg,
    const float* __restrict__ vfq, const float* __restrict__ vgq, float* __restrict__ out){
  __shared__ float scratch[4];
  int i = blockIdx.x*256 + threadIdx.x;
  float mf = lf[i], mg = lg[i];
  float vf = KVAR + vfq[i] - t2[i];
  float vg = KVAR + vgq[i] - t2[i];
  float dy = y[i] - mf;
  float e = -HLOG2PI - 0.5f*mg - 0.5f*(dy*dy + vf)*__expf(-mg + 0.5f*vg);
  float r = block_reduce(e, scratch);
  if (threadIdx.x==0) atomicAdd(out, -r);
}

extern "C" void kernel_launch(void* const* d_in, const int* in_sizes, int n_in,
                              void* d_out, int out_size, void* d_ws, size_t ws_size,
                              hipStream_t stream){
  const float* x   = (const float*)d_in[0];
  const float* y   = (const float*)d_in[1];
  const float* z   = (const float*)d_in[2];
  const float* qmf = (const float*)d_in[3];
  const float* qlf = (const float*)d_in[4];
  const float* qmg = (const float*)d_in[5];
  const float* qlg = (const float*)d_in[6];
  float* out = (float*)d_out;
  float* ws  = (float*)d_ws;

  float* kuu  = ws + OFF_KUU;
  float* linv = ws + OFF_LINV;
  float* wf   = ws + OFF_WF;
  float* wg   = ws + OFF_WG;
  float* tt   = ws + OFF_TT;
  float* af   = ws + OFF_AF;
  float* ag   = ws + OFF_AG;
  float* t2   = ws + OFF_T2;
  float* lf   = ws + OFF_LF;
  float* lg   = ws + OFF_LG;
  float* vfq  = ws + OFF_VFQ;
  float* vgq  = ws + OFF_VGQ;
  float* scal = ws + OFF_SCAL;

  hipMemsetAsync(out, 0, sizeof(float), stream);
  hipMemsetAsync(wf,  0, (size_t)2*MM*MM*sizeof(float), stream);          // wf+wg contiguous
  hipMemsetAsync(t2,  0, ((size_t)5*NN + 16)*sizeof(float), stream);      // t2,lf,lg,vfq,vgq,scal

  kuu_kernel<<<MM*MM/256, 256, 0, stream>>>(z, kuu);

  for (int kb=0; kb<NB; ++kb){
    chol_diag<<<1, 64, 0, stream>>>(kuu, kb);
    int rem = MM - (kb+1)*BB;
    if (rem > 0){
      trsm_panel<<<(rem+127)/128, 128, 0, stream>>>(kuu, kb);
      int tb = NB - kb - 1;
      syrk_update<<<dim3(tb, tb), 256, 0, stream>>>(kuu, kb);
    }
  }

  inv_diag<<<NB, 64, 0, stream>>>(kuu, linv);
  for (int d=1; d<NB; ++d) inv_off<<<NB-d, 256, 0, stream>>>(kuu, linv, d);

  w_kernel<<<dim3(NB, NB, 2), 256, 0, stream>>>(linv, qlf, qlg, wf, wg);
  alpha_kernel<<<dim3(MM, 2), 256, 0, stream>>>(linv, qmf, qmg, af, ag);
  red_small<<<1, 256, 0, stream>>>(kuu, qlf, qlg, af, ag, scal);
  redw_kernel<<<512, 256, 0, stream>>>(wf, wg, scal);
  kl_kernel<<<1, 1, 0, stream>>>(scal, out);

  tt_kernel<<<dim3(NN/128, NB), 256, 0, stream>>>(x, z, linv, tt);
  lin_kernel<<<dim3(NN/256, 8), 256, 0, stream>>>(tt, af, ag, t2, lf, lg);
  quad_kernel<<<dim3(NN/BB, NB), 256, 0, stream>>>(tt, wf, wg, vfq, vgq);
  final_kernel<<<NN/256, 256, 0, stream>>>(y, t2, lf, lg, vfq, vgq, out);
}

// Round 2
// 9763.561 us; speedup vs baseline: 1.3598x; 1.3598x over previous
//
#include <hip/hip_runtime.h>
#include <math.h>

// ChainedGP v2: split-bf16 MFMA for the two N*M^2 GEMMs.
// N=16384, M=2048, D=8, fp32 in/out. Workspace ~185 MB (overlaid).
#define NN 16384
#define MM 2048
#define DD 8
#define BB 64
#define NB 32            // MM/BB
#define SZB ((size_t)16777216)   // 2048*2048*4 bytes

constexpr float KVAR    = 1.0f;
constexpr float GAMMA   = 2.0f;      // 0.5/LS^2, LS=0.5
constexpr float KJITTER = 1e-6f;
constexpr float HLOG2PI = 0.91893853320467274178f;

using short8  = __attribute__((ext_vector_type(8))) short;
using float4v = __attribute__((ext_vector_type(4))) float;

__device__ __forceinline__ float4v f4zero(){ float4v v; v[0]=0.f; v[1]=0.f; v[2]=0.f; v[3]=0.f; return v; }

// fp32 -> bf16 hi (truncate) + bf16 lo (truncate of remainder); rel err ~2^-16
__device__ __forceinline__ void bfsplit(float v, short& h, short& lo){
  unsigned b = __float_as_uint(v);
  h = (short)(b >> 16);
  float hf = __uint_as_float(b & 0xFFFF0000u);
  lo = (short)(__float_as_uint(v - hf) >> 16);
}
__device__ __forceinline__ float bf2f(short s){
  return __uint_as_float(((unsigned)(unsigned short)s) << 16);
}
__device__ __forceinline__ float4v mfma3(short8 ah, short8 al, short8 bh, short8 bl, float4v c){
  c = __builtin_amdgcn_mfma_f32_16x16x32_bf16(ah, bh, c, 0, 0, 0);
  c = __builtin_amdgcn_mfma_f32_16x16x32_bf16(ah, bl, c, 0, 0, 0);
  c = __builtin_amdgcn_mfma_f32_16x16x32_bf16(al, bh, c, 0, 0, 0);
  return c;
}

// frag-linear storage: chunk = (outer>>4)*(Inner/32) + (inner>>5)
// pos = chunk*512 + (outer&15)*32 + (inner&31). One chunk = 1KB of bf16.

__device__ __forceinline__ float block_reduce(float v, float* scratch){
  int lane = threadIdx.x & 63;
  int w    = threadIdx.x >> 6;
  #pragma unroll
  for (int off=32; off; off>>=1) v += __shfl_down(v, off, 64);
  __syncthreads();
  if (lane==0) scratch[w] = v;
  __syncthreads();
  float r = 0.f;
  if (threadIdx.x < 4) r = scratch[threadIdx.x];
  if (w==0){ r += __shfl_down(r, 2, 64); r += __shfl_down(r, 1, 64); }
  return r;
}

// ---------- Kuu = rbf(z,z) + jitter I ----------
__global__ __launch_bounds__(256) void kuu_kernel(const float* __restrict__ z, float* __restrict__ kuu){
  int idx = blockIdx.x*256 + threadIdx.x;
  int i = idx >> 11, j = idx & 2047;
  float d2 = 0.f;
  #pragma unroll
  for (int d=0; d<DD; ++d){ float df = z[i*DD+d] - z[j*DD+d]; d2 += df*df; }
  float v = KVAR * __expf(-GAMMA*d2);
  if (i==j) v += KJITTER;
  kuu[(size_t)i*MM + j] = v;
}

// ---------- z fragments (B-operand, K=8 padded to 32) + |z|^2 ----------
__global__ __launch_bounds__(256) void zfrag_kernel(const float* __restrict__ z,
    short* __restrict__ zfh, short* __restrict__ zfl, float* __restrict__ zn2){
  int zr = blockIdx.x*256 + threadIdx.x;   // 2048 rows
  float v[DD]; float s = 0.f;
  #pragma unroll
  for (int d=0; d<DD; ++d){ v[d] = z[zr*DD + d]; s += v[d]*v[d]; }
  zn2[zr] = s;
  size_t base = (size_t)(zr >> 4)*512 + (zr & 15)*32;
  #pragma unroll
  for (int k=0; k<32; ++k){
    short h = 0, lo = 0;
    if (k < DD) bfsplit(v[k], h, lo);
    zfh[base + k] = h; zfl[base + k] = lo;
  }
}

// ---------- Cholesky: 64x64 diagonal block, single wave ----------
__global__ __launch_bounds__(64) void chol_diag(float* __restrict__ a, int kb){
  __shared__ float s[BB][BB+1];
  int lane = threadIdx.x;
  int base = kb*BB;
  for (int c=0;c<BB;++c) s[lane][c] = a[(size_t)(base+lane)*MM + base + c];
  __syncthreads();
  for (int j=0;j<BB;++j){
    if (lane==j) s[j][j] = sqrtf(fmaxf(s[j][j], 1e-20f));
    __syncthreads();
    if (lane>j) s[lane][j] /= s[j][j];
    __syncthreads();
    for (int c=j+1;c<=lane;++c) s[lane][c] -= s[lane][j]*s[c][j];
    __syncthreads();
  }
  for (int c=0;c<BB;++c) a[(size_t)(base+lane)*MM + base + c] = (c<=lane) ? s[lane][c] : 0.f;
}

// ---------- Cholesky: panel TRSM ----------
__global__ __launch_bounds__(128) void trsm_panel(float* __restrict__ a, int kb){
  __shared__ float lkk[BB][BB+1];
  __shared__ float xs[128][BB+1];
  int t = threadIdx.x;
  int base = kb*BB;
  for (int p=t;p<BB*BB;p+=128){ int i=p>>6, c=p&63; lkk[i][c] = a[(size_t)(base+i)*MM + base + c]; }
  int r = base + BB + blockIdx.x*128 + t;
  bool act = r < MM;
  size_t rowoff = act ? ((size_t)r*MM + base) : 0;
  for (int c=0;c<BB;++c) xs[t][c] = act ? a[rowoff + c] : 0.f;
  __syncthreads();
  for (int j=0;j<BB;++j){
    float s = xs[t][j];
    for (int i=0;i<j;++i) s -= xs[t][i]*lkk[j][i];
    xs[t][j] = s / lkk[j][j];
  }
  if (act) for (int c=0;c<BB;++c) a[rowoff + c] = xs[t][c];
}

// ---------- Cholesky: trailing SYRK ----------
__global__ __launch_bounds__(256) void syrk_update(float* __restrict__ a, int kb){
  int bi = kb + 1 + blockIdx.y;
  int bc = kb + 1 + blockIdx.x;
  if (bc > bi) return;
  __shared__ float P[BB][BB+1], Q[BB][BB+1];
  int t = threadIdx.x, tx = t&15, ty = t>>4;
  for (int p=t;p<BB*BB;p+=256){
    int i=p>>6, c=p&63;
    P[i][c] = a[(size_t)(bi*BB+i)*MM + kb*BB + c];
    Q[i][c] = a[(size_t)(bc*BB+i)*MM + kb*BB + c];
  }
  __syncthreads();
  float acc[4][4] = {};
  for (int k=0;k<BB;++k){
    float pr[4], qc[4];
    #pragma unroll
    for (int u=0;u<4;++u){ pr[u]=P[ty*4+u][k]; qc[u]=Q[tx*4+u][k]; }
    #pragma unroll
    for (int u=0;u<4;++u)
      #pragma unroll
      for (int v=0;v<4;++v) acc[u][v] += pr[u]*qc[v];
  }
  #pragma unroll
  for (int u=0;u<4;++u)
    #pragma unroll
    for (int v=0;v<4;++v)
      a[(size_t)(bi*BB+ty*4+u)*MM + bc*BB + tx*4+v] -= acc[u][v];
}

// ---------- invert diagonal blocks of Lk ----------
__global__ __launch_bounds__(64) void inv_diag(const float* __restrict__ lk, float* __restrict__ linv){
  __shared__ float L[BB][BB+1];
  __shared__ float X[BB][BB+1];
  int lane = threadIdx.x;
  int b = blockIdx.x;
  for (int c=0;c<BB;++c) L[lane][c] = lk[(size_t)(b*BB+lane)*MM + b*BB + c];
  __syncthreads();
  for (int j=0;j<BB;++j){
    float s = (j==lane) ? 1.f : 0.f;
    for (int k=lane;k<j;++k) s -= L[j][k]*X[k][lane];
    X[j][lane] = (j>=lane) ? s / L[j][j] : 0.f;
  }
  __syncthreads();
  for (int j=0;j<BB;++j) linv[(size_t)(b*BB+j)*MM + b*BB + lane] = X[j][lane];
}

// ---------- off-diagonal inversion ----------
__global__ __launch_bounds__(256) void inv_off(const float* __restrict__ lk, float* __restrict__ linv, int d){
  int bj = blockIdx.x;
  int bi = bj + d;
  __shared__ float As[BB][BB+1], Bs[BB][BB+1];
  int t=threadIdx.x, tx=t&15, ty=t>>4;
  float acc[4][4] = {};
  for (int bk=bj; bk<bi; ++bk){
    __syncthreads();
    for (int p=t;p<BB*BB;p+=256){
      int i=p>>6, c=p&63;
      As[i][c] = lk[(size_t)(bi*BB+i)*MM + bk*BB + c];
      Bs[i][c] = linv[(size_t)(bk*BB+i)*MM + bj*BB + c];
    }
    __syncthreads();
    for (int k=0;k<BB;++k){
      float ar[4], bc4[4];
      #pragma unroll
      for (int u=0;u<4;++u){ ar[u]=As[ty*4+u][k]; bc4[u]=Bs[k][tx*4+u]; }
      #pragma unroll
      for (int u=0;u<4;++u)
        #pragma unroll
        for (int v=0;v<4;++v) acc[u][v] += ar[u]*bc4[v];
    }
  }
  __syncthreads();
  #pragma unroll
  for (int u=0;u<4;++u)
    #pragma unroll
    for (int v=0;v<4;++v) As[ty*4+u][tx*4+v] = acc[u][v];
  for (int p=t;p<BB*BB;p+=256){
    int i=p>>6, c=p&63;
    Bs[i][c] = linv[(size_t)(bi*BB+i)*MM + bi*BB + c];
  }
  __syncthreads();
  float out[4][4] = {};
  for (int k=0;k<BB;++k){
    float xr[4], tc[4];
    #pragma unroll
    for (int u=0;u<4;++u){ xr[u]=Bs[ty*4+u][k]; tc[u]=As[k][tx*4+u]; }
    #pragma unroll
    for (int u=0;u<4;++u)
      #pragma unroll
      for (int v=0;v<4;++v) out[u][v] += xr[u]*tc[v];
  }
  #pragma unroll
  for (int u=0;u<4;++u)
    #pragma unroll
    for (int v=0;v<4;++v)
      linv[(size_t)(bi*BB+ty*4+u)*MM + bj*BB + tx*4+v] = -out[u][v];
}

// ---------- W = Linv @ tril(qL) ----------
__global__ __launch_bounds__(256) void w_kernel(const float* __restrict__ linv,
    const float* __restrict__ qlf, const float* __restrict__ qlg,
    float* __restrict__ wf, float* __restrict__ wg){
  int bj = blockIdx.x, bi = blockIdx.y;
  if (bi < bj) return;
  const float* ql = blockIdx.z ? qlg : qlf;
  float* w        = blockIdx.z ? wg  : wf;
  __shared__ float As[BB][BB+1], Bs[BB][BB+1];
  int t=threadIdx.x, tx=t&15, ty=t>>4;
  float acc[4][4] = {};
  for (int bk=bj; bk<=bi; ++bk){
    __syncthreads();
    for (int p=t;p<BB*BB;p+=256){
      int i=p>>6, c=p&63;
      As[i][c] = linv[(size_t)(bi*BB+i)*MM + bk*BB + c];
      float qv = ql[(size_t)(bk*BB+i)*MM + bj*BB + c];
      if (bk==bj && i<c) qv = 0.f;
      Bs[i][c] = qv;
    }
    __syncthreads();
    for (int k=0;k<BB;++k){
      float ar[4], bc4[4];
      #pragma unroll
      for (int u=0;u<4;++u){ ar[u]=As[ty*4+u][k]; bc4[u]=Bs[k][tx*4+u]; }
      #pragma unroll
      for (int u=0;u<4;++u)
        #pragma unroll
        for (int v=0;v<4;++v) acc[u][v] += ar[u]*bc4[v];
    }
  }
  #pragma unroll
  for (int u=0;u<4;++u)
    #pragma unroll
    for (int v=0;v<4;++v)
      w[(size_t)(bi*BB+ty*4+u)*MM + bj*BB + tx*4+v] = acc[u][v];
}

// ---------- alpha = Linv @ qm ----------
__global__ __launch_bounds__(256) void alpha_kernel(const float* __restrict__ linv,
    const float* __restrict__ qmf, const float* __restrict__ qmg,
    float* __restrict__ af, float* __restrict__ ag){
  __shared__ float scratch[4];
  int r = blockIdx.x;
  const float* qm = blockIdx.y ? qmg : qmf;
  float* a        = blockIdx.y ? ag  : af;
  float s = 0.f;
  for (int c=threadIdx.x;c<=r;c+=256) s += linv[(size_t)r*MM + c]*qm[c];
  s = block_reduce(s, scratch);
  if (threadIdx.x==0) a[r] = s;
}

// ---------- small reductions ----------
__global__ __launch_bounds__(256) void red_small(const float* __restrict__ lk,
    const float* __restrict__ qlf, const float* __restrict__ qlg,
    const float* __restrict__ af, const float* __restrict__ ag,
    float* __restrict__ scal){
  __shared__ float scratch[4];
  float ldk=0, ldf=0, ldg=0, a2f=0, a2g=0;
  for (int i=threadIdx.x;i<MM;i+=256){
    ldk += __logf(lk[(size_t)i*MM+i]);
    ldf += __logf(fabsf(qlf[(size_t)i*MM+i]));
    ldg += __logf(fabsf(qlg[(size_t)i*MM+i]));
    float v = af[i]; a2f += v*v;
    v = ag[i];       a2g += v*v;
  }
  float r;
  r = block_reduce(ldk, scratch); if (threadIdx.x==0) scal[0] = 2.f*r;
  r = block_reduce(ldf, scratch); if (threadIdx.x==0) scal[1] = 2.f*r;
  r = block_reduce(ldg, scratch); if (threadIdx.x==0) scal[2] = 2.f*r;
  r = block_reduce(a2f, scratch); if (threadIdx.x==0) scal[3] = r;
  r = block_reduce(a2g, scratch); if (threadIdx.x==0) scal[4] = r;
}

// ---------- ||W_f||^2, ||W_g||^2 ----------
__global__ __launch_bounds__(256) void redw_kernel(const float* __restrict__ wf,
    const float* __restrict__ wg, float* __restrict__ scal){
  __shared__ float scratch[4];
  size_t start  = (size_t)blockIdx.x*256 + threadIdx.x;
  size_t stride = (size_t)gridDim.x*256;
  float sf=0, sg=0;
  for (size_t p=start;p<(size_t)MM*MM;p+=stride){
    float v=wf[p]; sf += v*v;
    v=wg[p];       sg += v*v;
  }
  float r = block_reduce(sf, scratch);
  if (threadIdx.x==0) atomicAdd(&scal[5], r);
  r = block_reduce(sg, scratch);
  if (threadIdx.x==0) atomicAdd(&scal[6], r);
}

__global__ void kl_kernel(const float* __restrict__ scal, float* __restrict__ out){
  float klf = 0.5f*(scal[5] + scal[3] - (float)MM + scal[0] - scal[1]);
  float klg = 0.5f*(scal[6] + scal[4] - (float)MM + scal[0] - scal[2]);
  out[0] += klf + klg;
}

// ---------- split fp32 (row-major, outer=row) -> frag-order bf16 hi/lo ----------
__global__ __launch_bounds__(256) void split_rowmajor(const float* __restrict__ src,
    short* __restrict__ dh, short* __restrict__ dl){
  int p = blockIdx.x*256 + threadIdx.x;        // M*M positions
  int chunk = p >> 9, wi = p & 511;
  int mo = chunk >> 6, ko = chunk & 63;        // Inner/32 = 64
  int row = mo*16 + (wi >> 5), col = ko*32 + (wi & 31);
  float v = src[(size_t)row*MM + col];
  short h, lo; bfsplit(v, h, lo);
  dh[p] = h; dl[p] = lo;
}

// ---------- split fp32 (outer=col: W as B-operand) via LDS transpose ----------
__global__ __launch_bounds__(256) void split_transpose(const float* __restrict__ wf,
    const float* __restrict__ wg,
    short* __restrict__ fh, short* __restrict__ fl,
    short* __restrict__ gh, short* __restrict__ gl){
  __shared__ float tile[32][33];
  int t = threadIdx.x;
  int mb = blockIdx.x, kb = blockIdx.y;
  const float* src = blockIdx.z ? wg : wf;
  short* dh = blockIdx.z ? gh : fh;
  short* dl = blockIdx.z ? gl : fl;
  #pragma unroll
  for (int k=0;k<4;++k){
    int idx = t + k*256;
    int lr = idx >> 5, lc = idx & 31;
    tile[lr][lc] = src[(size_t)(kb*32+lr)*MM + mb*32 + lc];
  }
  __syncthreads();
  #pragma unroll
  for (int e=0;e<4;++e){
    int p = t*4 + e;
    int c = p >> 9, wi = p & 511;
    int i = (wi >> 5) & 15, kk = wi & 31;
    float v = tile[kk][c*16 + i];
    short h, lo; bfsplit(v, h, lo);
    size_t gp = ((size_t)(mb*2 + c)*64 + kb)*512 + wi;
    dh[gp] = h; dl[gp] = lo;
  }
}

// ---------- T^T = Kfu @ Linv^T via split-bf16 MFMA; Kfu from in-register split-MFMA S ----------
// WG tile 128n x 128m, 4 waves (2x2 of 64x64). Writes frag-order tt_hi/lo.
__global__ __launch_bounds__(256, 2) void tt_mfma(
    const float* __restrict__ x, const float* __restrict__ zn2,
    const short* __restrict__ zfh, const short* __restrict__ zfl,
    const short* __restrict__ lvh, const short* __restrict__ lvl,
    short* __restrict__ tth, short* __restrict__ ttl){
  __shared__ __align__(16) short lAh[8192], lAl[8192], lBh[8192], lBl[8192];
  int t = threadIdx.x;
  int l = t & 63, w = t >> 6;
  int istrip = blockIdx.x, bj2 = blockIdx.y;
  int li = l & 15, q = l >> 4;
  int lofs = li*32 + q*8;
  int wn4 = (w>>1)*4, wm4 = (w&1)*4;

  // x A-frags for S phase (wave w covers rows w*32..w*32+32); quarters 1..3 = zero pad (K=8)
  short8 xh[2], xl[2];
  float xn2v[8];
  {
    float xn2t[2];
    #pragma unroll
    for (int tn=0; tn<2; ++tn){
      int n = istrip*128 + w*32 + tn*16 + li;
      const float4* xp = (const float4*)(x + (size_t)n*DD);
      float4 p0 = xp[0], p1 = xp[1];
      float v[8] = {p0.x,p0.y,p0.z,p0.w,p1.x,p1.y,p1.z,p1.w};
      float s = 0.f;
      #pragma unroll
      for (int d=0; d<8; ++d) s += v[d]*v[d];
      xn2t[tn] = s;
      short8 hh, ll;
      #pragma unroll
      for (int j=0; j<8; ++j){
        short h=0, lo=0;
        if (q==0) bfsplit(v[j], h, lo);
        hh[j]=h; ll[j]=lo;
      }
      xh[tn]=hh; xl[tn]=ll;
    }
    #pragma unroll
    for (int tn=0; tn<2; ++tn)
      #pragma unroll
      for (int r=0; r<4; ++r)
        xn2v[tn*4+r] = __shfl(xn2t[tn], q*4 + r, 64);
  }

  float4v acc[4][4];
  #pragma unroll
  for (int i=0;i<4;++i)
    #pragma unroll
    for (int j=0;j<4;++j) acc[i][j] = f4zero();

  int nkt = 2*bj2 + 2;
  for (int bk=0; bk<nkt; ++bk){
    __syncthreads();
    // --- S phase: Kfu[128n x 64k] -> lA frags ---
    {
      short8 zh[4], zl[4];
      float zt2[4];
      #pragma unroll
      for (int tz=0; tz<4; ++tz){
        size_t zo = (size_t)(bk*4 + tz)*512 + lofs;
        zh[tz] = *(const short8*)(zfh + zo);
        zl[tz] = *(const short8*)(zfl + zo);
        zt2[tz] = zn2[bk*64 + tz*16 + li];
      }
      #pragma unroll
      for (int tn=0; tn<2; ++tn){
        #pragma unroll
        for (int tz=0; tz<4; ++tz){
          float4v s4 = mfma3(xh[tn], xl[tn], zh[tz], zl[tz], f4zero());
          #pragma unroll
          for (int r=0; r<4; ++r){
            float e = __expf(4.f*s4[r] - 2.f*(xn2v[tn*4+r] + zt2[tz]));
            short h, lo; bfsplit(e, h, lo);
            int pos = ((w*2+tn)*2 + (tz>>1))*512 + (q*4+r)*32 + (tz&1)*16 + li;
            lAh[pos] = h; lAl[pos] = lo;
          }
        }
      }
    }
    // --- stage Linv tile (128m x 64k) frag chunks ---
    #pragma unroll
    for (int c4 = t; c4 < 1024; c4 += 256){
      int ch = c4 >> 6, wdi = c4 & 63;
      size_t g = ((size_t)(bj2*8 + (ch>>1))*64 + (size_t)(bk*2 + (ch&1)))*64 + wdi;
      ((uint4*)lBh)[c4] = ((const uint4*)lvh)[g];
      ((uint4*)lBl)[c4] = ((const uint4*)lvl)[g];
    }
    __syncthreads();
    // --- main MFMA ---
    #pragma unroll
    for (int s=0; s<2; ++s){
      short8 ah[4], al[4], bh[4], bl[4];
      #pragma unroll
      for (int tn=0; tn<4; ++tn){
        int off = ((wn4+tn)*2 + s)*512 + lofs;
        ah[tn] = *(const short8*)&lAh[off];
        al[tn] = *(const short8*)&lAl[off];
      }
      #pragma unroll
      for (int tm=0; tm<4; ++tm){
        int off = ((wm4+tm)*2 + s)*512 + lofs;
        bh[tm] = *(const short8*)&lBh[off];
        bl[tm] = *(const short8*)&lBl[off];
      }
      #pragma unroll
      for (int tn=0; tn<4; ++tn)
        #pragma unroll
        for (int tm=0; tm<4; ++tm)
          acc[tn][tm] = mfma3(ah[tn], al[tn], bh[tm], bl[tm], acc[tn][tm]);
    }
  }
  // --- epilogue: frag-order global store (outer=n, inner=m) ---
  #pragma unroll
  for (int tn=0; tn<4; ++tn){
    int no_g = istrip*8 + wn4 + tn;
    #pragma unroll
    for (int tm=0; tm<4; ++tm){
      int mo_g = bj2*4 + (w&1)*2 + (tm>>1);
      size_t cb = ((size_t)no_g*64 + mo_g)*512;
      #pragma unroll
      for (int r=0; r<4; ++r){
        short h, lo; bfsplit(acc[tn][tm][r], h, lo);
        size_t pos = cb + (q*4+r)*32 + (tm&1)*16 + li;
        tth[pos] = h; ttl[pos] = lo;
      }
    }
  }
}

// ---------- per-row ||t||^2, t.alpha (reads frag-order tt hi/lo) ----------
__global__ __launch_bounds__(256) void lin_v2(const short* __restrict__ tth,
    const short* __restrict__ ttl, const float* __restrict__ af, const float* __restrict__ ag,
    float* __restrict__ t2, float* __restrict__ lf, float* __restrict__ lg){
  int t = threadIdx.x;
  int w = t >> 6, l = t & 63;
  int n = blockIdx.x*4 + w;
  int g = l >> 2, j = l & 3;
  float s2=0.f, sf=0.f, sg=0.f;
  #pragma unroll
  for (int it=0; it<4; ++it){
    int ck = g + it*16;
    size_t off = ((size_t)(n>>4)*64 + ck)*512 + (n&15)*32 + j*8;
    short8 h8 = *(const short8*)(tth + off);
    short8 l8 = *(const short8*)(ttl + off);
    int m0 = ck*32 + j*8;
    float4 a0 = *(const float4*)(af + m0), a1 = *(const float4*)(af + m0 + 4);
    float4 g0 = *(const float4*)(ag + m0), g1 = *(const float4*)(ag + m0 + 4);
    float av[8] = {a0.x,a0.y,a0.z,a0.w,a1.x,a1.y,a1.z,a1.w};
    float gv[8] = {g0.x,g0.y,g0.z,g0.w,g1.x,g1.y,g1.z,g1.w};
    #pragma unroll
    for (int e=0; e<8; ++e){
      float tv = bf2f(h8[e]) + bf2f(l8[e]);
      s2 += tv*tv; sf += tv*av[e]; sg += tv*gv[e];
    }
  }
  #pragma unroll
  for (int off=32; off; off>>=1){
    s2 += __shfl_down(s2, off, 64);
    sf += __shfl_down(sf, off, 64);
    sg += __shfl_down(sg, off, 64);
  }
  if (l==0){ t2[n] = s2; lf[n] = sf; lg[n] = sg; }
}

// ---------- U = T^T @ W (both GPs via blockIdx.z); accumulate row-sums of U^2 ----------
// WG tile 128n x 128m, 4 waves (2x2 of 64x64), K from bj2*128 to M.
__global__ __launch_bounds__(256, 2) void quad_mfma(
    const short* __restrict__ tth, const short* __restrict__ ttl,
    const short* __restrict__ wfh, const short* __restrict__ wfl,
    const short* __restrict__ wgh, const short* __restrict__ wgl,
    float* __restrict__ vfq, float* __restrict__ vgq){
  __shared__ __align__(16) short lAh[8192], lAl[8192], lBh[8192], lBl[8192];
  int t = threadIdx.x, l = t & 63, w = t >> 6;
  int istrip = blockIdx.x, bj2 = blockIdx.y;
  const short* gbh = blockIdx.z ? wgh : wfh;
  const short* gbl = blockIdx.z ? wgl : wfl;
  float* vq = blockIdx.z ? vgq : vfq;
  int li = l & 15, q = l >> 4;
  int lofs = li*32 + q*8;
  int wn4 = (w>>1)*4, wm4 = (w&1)*4;

  float4v acc[4][4];
  #pragma unroll
  for (int i=0;i<4;++i)
    #pragma unroll
    for (int j=0;j<4;++j) acc[i][j] = f4zero();

  for (int bk=2*bj2; bk<32; ++bk){
    __syncthreads();
    #pragma unroll
    for (int c4 = t; c4 < 1024; c4 += 256){
      int ch = c4 >> 6, wdi = c4 & 63;
      size_t ga = ((size_t)(istrip*8 + (ch>>1))*64 + (size_t)(bk*2 + (ch&1)))*64 + wdi;
      ((uint4*)lAh)[c4] = ((const uint4*)tth)[ga];
      ((uint4*)lAl)[c4] = ((const uint4*)ttl)[ga];
      size_t gb = ((size_t)(bj2*8 + (ch>>1))*64 + (size_t)(bk*2 + (ch&1)))*64 + wdi;
      ((uint4*)lBh)[c4] = ((const uint4*)gbh)[gb];
      ((uint4*)lBl)[c4] = ((const uint4*)gbl)[gb];
    }
    __syncthreads();
    #pragma unroll
    for (int s=0; s<2; ++s){
      short8 ah[4], al[4], bh[4], bl[4];
      #pragma unroll
      for (int tn=0; tn<4; ++tn){
        int off = ((wn4+tn)*2 + s)*512 + lofs;
        ah[tn] = *(const short8*)&lAh[off];
        al[tn] = *(const short8*)&lAl[off];
      }
      #pragma unroll
      for (int tm=0; tm<4; ++tm){
        int off = ((wm4+tm)*2 + s)*512 + lofs;
        bh[tm] = *(const short8*)&lBh[off];
        bl[tm] = *(const short8*)&lBl[off];
      }
      #pragma unroll
      for (int tn=0; tn<4; ++tn)
        #pragma unroll
        for (int tm=0; tm<4; ++tm)
          acc[tn][tm] = mfma3(ah[tn], al[tn], bh[tm], bl[tm], acc[tn][tm]);
    }
  }
  // row-sums of squares; reduce over the 16 lanes of each quarter-row group
  float rs[16];
  #pragma unroll
  for (int tn=0; tn<4; ++tn)
    #pragma unroll
    for (int r=0; r<4; ++r){
      float s = 0.f;
      #pragma unroll
      for (int tm=0; tm<4; ++tm){ float v = acc[tn][tm][r]; s += v*v; }
      rs[tn*4+r] = s;
    }
  #pragma unroll
  for (int off=8; off; off>>=1)
    #pragma unroll
    for (int k=0; k<16; ++k) rs[k] += __shfl_down(rs[k], off, 16);
  if (li == 0){
    #pragma unroll
    for (int tn=0; tn<4; ++tn)
      #pragma unroll
      for (int r=0; r<4; ++r){
        int n = istrip*128 + (w>>1)*64 + tn*16 + q*4 + r;
        atomicAdd(&vq[n], rs[tn*4+r]);
      }
  }
}

// ---------- expectation term + reduce ----------
__global__ __launch_bounds__(256) void final_kernel(const float* __restrict__ y,
    const float* __restrict__ t2, const float* __restrict__ lf, const float* __restrict__ lg,
    const float* __restrict__ vfq, const float* __restrict__ vgq, float* __restrict__ out){
  __shared__ float scratch[4];
  int i = blockIdx.x*256 + threadIdx.x;
  float mf = lf[i], mg = lg[i];
  float vf = KVAR + vfq[i] - t2[i];
  float vg = KVAR + vgq[i] - t2[i];
  float dy = y[i] - mf;
  float e = -HLOG2PI - 0.5f*mg - 0.5f*(dy*dy + vf)*__expf(-mg + 0.5f*vg);
  float r = block_reduce(e, scratch);
  if (threadIdx.x==0) atomicAdd(out, -r);
}

extern "C" void kernel_launch(void* const* d_in, const int* in_sizes, int n_in,
                              void* d_out, int out_size, void* d_ws, size_t ws_size,
                              hipStream_t stream){
  const float* x   = (const float*)d_in[0];
  const float* y   = (const float*)d_in[1];
  const float* z   = (const float*)d_in[2];
  const float* qmf = (const float*)d_in[3];
  const float* qlf = (const float*)d_in[4];
  const float* qmg = (const float*)d_in[5];
  const float* qlg = (const float*)d_in[6];
  float* out = (float*)d_out;
  char* Bw = (char*)d_ws;

  // overlaid workspace (total ~185 MB)
  float* kuu  = (float*)Bw;                    // region K; later linv frag hi/lo
  float* linv = (float*)(Bw + SZB);            // region L; later wf frag hi/lo
  float* wf   = (float*)(Bw + 2*SZB);          // region WF; later wg frag hi/lo
  float* wg   = (float*)(Bw + 3*SZB);          // region WG; later overwritten by tt
  short* lvh  = (short*)Bw;
  short* lvl  = (short*)(Bw + SZB/2);
  short* wfh  = (short*)(Bw + SZB);
  short* wfl  = (short*)(Bw + SZB + SZB/2);
  short* wgh  = (short*)(Bw + 2*SZB);
  short* wgl  = (short*)(Bw + 2*SZB + SZB/2);
  short* tth  = (short*)(Bw + 3*SZB);
  short* ttl  = (short*)(Bw + 3*SZB + (size_t)NN*MM*2);
  float* sm   = (float*)(Bw + 3*SZB + (size_t)NN*MM*4);
  float* af = sm;          float* ag = af + MM;
  float* t2 = ag + MM;     float* lf = t2 + NN;   float* lg = lf + NN;
  float* vfq = lg + NN;    float* vgq = vfq + NN; float* scal = vgq + NN;
  float* zn2 = scal + 16;
  short* zfh = (short*)(zn2 + MM);
  short* zfl = zfh + MM*32;

  hipMemsetAsync(out, 0, sizeof(float), stream);
  hipMemsetAsync(vfq, 0, (size_t)(2*NN + 16)*sizeof(float), stream);
  hipMemsetAsync(wf, 0, 2*SZB, stream);     // wf+wg fp32 (upper blocks must be 0)
  hipMemsetAsync(linv, 0, SZB, stream);     // upper blocks must be 0

  kuu_kernel<<<MM*MM/256, 256, 0, stream>>>(z, kuu);
  zfrag_kernel<<<MM/256, 256, 0, stream>>>(z, zfh, zfl, zn2);

  for (int kb=0; kb<NB; ++kb){
    chol_diag<<<1, 64, 0, stream>>>(kuu, kb);
    int rem = MM - (kb+1)*BB;
    if (rem > 0){
      trsm_panel<<<(rem+127)/128, 128, 0, stream>>>(kuu, kb);
      int tb = NB - kb - 1;
      syrk_update<<<dim3(tb, tb), 256, 0, stream>>>(kuu, kb);
    }
  }

  inv_diag<<<NB, 64, 0, stream>>>(kuu, linv);
  for (int d=1; d<NB; ++d) inv_off<<<NB-d, 256, 0, stream>>>(kuu, linv, d);

  w_kernel<<<dim3(NB, NB, 2), 256, 0, stream>>>(linv, qlf, qlg, wf, wg);
  alpha_kernel<<<dim3(MM, 2), 256, 0, stream>>>(linv, qmf, qmg, af, ag);
  red_small<<<1, 256, 0, stream>>>(kuu, qlf, qlg, af, ag, scal);
  redw_kernel<<<512, 256, 0, stream>>>(wf, wg, scal);
  kl_kernel<<<1, 1, 0, stream>>>(scal, out);

  // splits (note overlay order: kuu/linv/wf fp32 are dead by the time they're overwritten)
  split_rowmajor<<<MM*MM/256, 256, 0, stream>>>(linv, lvh, lvl);
  split_transpose<<<dim3(MM/32, MM/32, 2), 256, 0, stream>>>(wf, wg, wfh, wfl, wgh, wgl);

  tt_mfma<<<dim3(NN/128, MM/128), 256, 0, stream>>>(x, zn2, zfh, zfl, lvh, lvl, tth, ttl);
  lin_v2<<<NN/4, 256, 0, stream>>>(tth, ttl, af, ag, t2, lf, lg);
  quad_mfma<<<dim3(NN/128, MM/128, 2), 256, 0, stream>>>(tth, ttl, wfh, wfl, wgh, wgl, vfq, vgq);
  final_kernel<<<NN/256, 256, 0, stream>>>(y, t2, lf, lg, vfq, vgq, out);
}

// Round 5
// 6487.828 us; speedup vs baseline: 2.0464x; 1.5049x over previous
//
#include <hip/hip_runtime.h>
#include <math.h>

// ChainedGP v5: v4 with the cooperative launch replaced by a plain launch +
// software device-scope grid barrier. Theory: hipLaunchCooperativeKernel is
// not stream-capture-legal; round 4 was the first run to reach graph capture
// (round 3 failed correctness first) and the container died there, twice.
// 256 blocks x 33.5KB LDS = 4 blocks/CU capacity -> all co-resident, spin safe.
#define NN 16384
#define MM 2048
#define DD 8
#define NB 32                     // MM/64
#define GRIDN 256                 // factor kernel grid (co-resident)
#define SZB ((size_t)16777216)    // 2048*2048*4 bytes

constexpr float HLOG2PI = 0.91893853320467274178f;

using short8  = __attribute__((ext_vector_type(8))) short;
using float4v = __attribute__((ext_vector_type(4))) float;

__device__ __forceinline__ float4v f4zero(){ float4v v; v[0]=0.f; v[1]=0.f; v[2]=0.f; v[3]=0.f; return v; }

// fp32 -> bf16 hi (truncate) + bf16 lo (truncate of remainder); rel err ~2^-16
__device__ __forceinline__ void bfsplit(float v, short& h, short& lo){
  unsigned b = __float_as_uint(v);
  h = (short)(b >> 16);
  float hf = __uint_as_float(b & 0xFFFF0000u);
  lo = (short)(__float_as_uint(v - hf) >> 16);
}
__device__ __forceinline__ float bf2f(short s){
  return __uint_as_float(((unsigned)(unsigned short)s) << 16);
}
__device__ __forceinline__ float4v mfma3(short8 ah, short8 al, short8 bh, short8 bl, float4v c){
  c = __builtin_amdgcn_mfma_f32_16x16x32_bf16(ah, bh, c, 0, 0, 0);
  c = __builtin_amdgcn_mfma_f32_16x16x32_bf16(ah, bl, c, 0, 0, 0);
  c = __builtin_amdgcn_mfma_f32_16x16x32_bf16(al, bh, c, 0, 0, 0);
  return c;
}

// software grid barrier: monotonic counter, per-block generation.
// Requires all GRIDN blocks co-resident (guaranteed by LDS/VGPR budget).
__device__ __forceinline__ void gbar(int* cnt, int& gen){
  __syncthreads();
  if (threadIdx.x == 0){
    __threadfence();                       // release prior writes device-wide
    ++gen;
    atomicAdd(cnt, 1);
    const int target = gen * GRIDN;
    while (atomicAdd(cnt, 0) < target) __builtin_amdgcn_s_sleep(8);
    __threadfence();                       // acquire
  }
  __syncthreads();
}

__device__ __forceinline__ float block_reduce(float v, float* scratch){
  int lane = threadIdx.x & 63;
  int w    = threadIdx.x >> 6;
  #pragma unroll
  for (int off=32; off; off>>=1) v += __shfl_down(v, off, 64);
  __syncthreads();
  if (lane==0) scratch[w] = v;
  __syncthreads();
  float r = 0.f;
  if (threadIdx.x < 4) r = scratch[threadIdx.x];
  if (w==0){ r += __shfl_down(r, 2, 64); r += __shfl_down(r, 1, 64); }
  return r;
}

// 64x64 tile micro-kernels (256 thr, 4x4 per thread)
__device__ __forceinline__ void tile_gemm_step(float acc[4][4], const float (*As)[65], const float (*Bs)[65], int tx, int ty){
  for (int k=0;k<64;++k){
    float ar[4], bc4[4];
    #pragma unroll
    for (int u=0;u<4;++u){ ar[u]=As[ty*4+u][k]; bc4[u]=Bs[k][tx*4+u]; }
    #pragma unroll
    for (int u=0;u<4;++u)
      #pragma unroll
      for (int v=0;v<4;++v) acc[u][v] += ar[u]*bc4[v];
  }
}
__device__ __forceinline__ void tile_syrk_step(float acc[4][4], const float (*P)[65], const float (*Q)[65], int tx, int ty){
  for (int k=0;k<64;++k){
    float pr[4], qc[4];
    #pragma unroll
    for (int u=0;u<4;++u){ pr[u]=P[ty*4+u][k]; qc[u]=Q[tx*4+u][k]; }
    #pragma unroll
    for (int u=0;u<4;++u)
      #pragma unroll
      for (int v=0;v<4;++v) acc[u][v] += pr[u]*qc[v];
  }
}

// ================= fused factorization kernel (plain launch) =================
// Phases: Kuu | 32x(diag+trsm | syrk) | inv_diag | 5x(GEMM1|GEMM2) | W+alpha
__global__ __launch_bounds__(256) void factor_coop(
    const float* __restrict__ z,
    const float* __restrict__ qlf, const float* __restrict__ qlg,
    const float* __restrict__ qmf, const float* __restrict__ qmg,
    float* __restrict__ kuu, float* __restrict__ linv,
    float* __restrict__ wf, float* __restrict__ wg,
    float* __restrict__ af, float* __restrict__ ag,
    float* __restrict__ ptmp, float* __restrict__ lkdiag,
    int* __restrict__ bar)
{
  __shared__ float As[64][65];
  __shared__ float Bs[64][65];
  __shared__ float sd[64];
  const int bid = blockIdx.x, t = threadIdx.x;
  const int tx = t & 15, ty = t >> 4;
  int gen = 0;

  // ---- phase 0: Kuu = rbf(z,z) + jitter*I ----
  {
    float zr[64];
    int r0 = bid*8;
    #pragma unroll
    for (int rr=0; rr<8; ++rr)
      #pragma unroll
      for (int d=0; d<8; ++d) zr[rr*8+d] = z[(r0+rr)*8 + d];
    #pragma unroll
    for (int cc=0; cc<8; ++cc){
      int c = cc*256 + t;
      float zc[8];
      #pragma unroll
      for (int d=0; d<8; ++d) zc[d] = z[c*8+d];
      #pragma unroll
      for (int rr=0; rr<8; ++rr){
        float d2=0.f;
        #pragma unroll
        for (int d=0; d<8; ++d){ float df=zr[rr*8+d]-zc[d]; d2 += df*df; }
        float v = __expf(-2.f*d2);
        if (r0+rr == c) v += 1e-6f;
        kuu[(size_t)(r0+rr)*MM + c] = v;
      }
    }
  }
  gbar(bar, gen);

  // ---- phase 1: blocked Cholesky (panels in kuu; factored diagonals -> lkdiag) ----
  // All active blocks factor the diag redundantly in LDS from the SAME
  // (never-written-this-phase) kuu data; only bid 0 stores the factored
  // block, and to lkdiag — never back into kuu (v3 raced here -> NaN).
  for (int kb=0; kb<NB; ++kb){
    int R = MM - (kb+1)*64;
    int nact = (R + 255) >> 8; if (nact < 1) nact = 1;
    if (bid < nact){
      for (int p=t; p<4096; p+=256){ int i=p>>6, c=p&63;
        As[i][c] = kuu[(size_t)(kb*64+i)*MM + kb*64 + c]; }
      __syncthreads();
      for (int j=0; j<64; ++j){
        if (t==j) As[j][j] = sqrtf(fmaxf(As[j][j], 1e-20f));
        __syncthreads();
        if (t<64 && t>j) As[t][j] /= As[j][j];
        __syncthreads();
        if (t<64 && t>j) for (int c=j+1; c<=t; ++c) As[t][c] -= As[t][j]*As[c][j];
        __syncthreads();
      }
      if (t<64) sd[t] = 1.f / As[t][t];
      __syncthreads();
      if (bid==0){
        for (int p=t; p<4096; p+=256){ int i=p>>6, c=p&63;
          lkdiag[kb*4096 + p] = (c<=i) ? As[i][c] : 0.f; }
      }
      // register-resident TRSM: one row per thread, update form
      int row = (kb+1)*64 + bid*256 + t;
      if (row < MM){
        float xr[64];
        float* ap = kuu + (size_t)row*MM + kb*64;
        #pragma unroll
        for (int c4=0; c4<16; ++c4) *(float4*)&xr[c4*4] = *(const float4*)&ap[c4*4];
        #pragma unroll
        for (int j=0; j<64; ++j){
          float xj = xr[j]*sd[j];
          xr[j] = xj;
          #pragma unroll
          for (int c=j+1; c<64; ++c) xr[c] -= xj*As[c][j];
        }
        #pragma unroll
        for (int c4=0; c4<16; ++c4) *(float4*)&ap[c4*4] = *(float4*)&xr[c4*4];
      }
    }
    gbar(bar, gen);
    // trailing SYRK: A[bi,bc] -= P_bi * P_bc^T  (lower blocks only)
    int T = NB-1 - kb;
    int ntiles = T*(T+1)/2;
    for (int idx=bid; idx<ntiles; idx+=GRIDN){
      int r=0; while ((r+1)*(r+2)/2 <= idx) ++r;
      int c = idx - r*(r+1)/2;
      int bi = kb+1+r, bc = kb+1+c;
      __syncthreads();
      for (int p=t; p<4096; p+=256){ int i=p>>6, cc=p&63;
        As[i][cc] = kuu[(size_t)(bi*64+i)*MM + kb*64 + cc];
        Bs[i][cc] = kuu[(size_t)(bc*64+i)*MM + kb*64 + cc]; }
      __syncthreads();
      float acc[4][4] = {};
      tile_syrk_step(acc, As, Bs, tx, ty);
      #pragma unroll
      for (int u=0;u<4;++u)
        #pragma unroll
        for (int v=0;v<4;++v)
          kuu[(size_t)(bi*64+ty*4+u)*MM + bc*64 + tx*4+v] -= acc[u][v];
    }
    gbar(bar, gen);
  }

  // ---- phase 2: invert 64x64 diagonal blocks (from lkdiag; zeros in upper) ----
  if (bid < NB){
    int b = bid;
    for (int p=t; p<4096; p+=256)
      As[p>>6][p&63] = lkdiag[b*4096 + p];
    __syncthreads();
    if (t < 64){
      for (int j=0;j<64;++j){
        float s = (j==t)?1.f:0.f;
        for (int k=t;k<j;++k) s -= As[j][k]*Bs[k][t];
        Bs[j][t] = (j>=t)? s/As[j][j] : 0.f;
      }
    }
    __syncthreads();
    for (int p=t;p<4096;p+=256){ int i=p>>6, c=p&63;
      linv[(size_t)(b*64+i)*MM + b*64 + c] = Bs[i][c]; }
  }
  gbar(bar, gen);

  // ---- phase 3: recursive-doubling inversion: X21 = -X22 * A21 * X11 ----
  for (int s=0; s<5; ++s){
    int nb = 1<<s, mc = 16>>s, b = 64<<s;
    int tiles = mc*nb*nb;
    // GEMM1: P = A21 * X11   (X11 lower-tri: k >= tj)
    for (int idx=bid; idx<tiles; idx+=GRIDN){
      int m = idx/(nb*nb), r2 = idx%(nb*nb);
      int ti = r2/nb, tj = r2%nb;
      int rb = m*2*nb + nb + ti, cb0 = m*2*nb;
      float acc[4][4]={};
      for (int k=tj; k<nb; ++k){
        __syncthreads();
        for (int p=t;p<4096;p+=256){ int i=p>>6, c=p&63;
          As[i][c] = kuu[(size_t)(rb*64+i)*MM + (cb0+k)*64 + c];
          Bs[i][c] = linv[(size_t)((cb0+k)*64+i)*MM + (cb0+tj)*64 + c]; }
        __syncthreads();
        tile_gemm_step(acc, As, Bs, tx, ty);
      }
      float* pm = ptmp + (size_t)m*b*b;
      #pragma unroll
      for (int u=0;u<4;++u)
        #pragma unroll
        for (int v=0;v<4;++v)
          pm[(size_t)(ti*64+ty*4+u)*b + tj*64 + tx*4+v] = acc[u][v];
    }
    gbar(bar, gen);
    // GEMM2: X21 = -X22 * P   (X22 lower-tri: k <= ti)
    for (int idx=bid; idx<tiles; idx+=GRIDN){
      int m = idx/(nb*nb), r2 = idx%(nb*nb);
      int ti = r2/nb, tj = r2%nb;
      int rb = m*2*nb + nb + ti;
      const float* pm = ptmp + (size_t)m*b*b;
      float acc[4][4]={};
      for (int k=0; k<=ti; ++k){
        __syncthreads();
        for (int p=t;p<4096;p+=256){ int i=p>>6, c=p&63;
          As[i][c] = linv[(size_t)(rb*64+i)*MM + (m*2*nb+nb+k)*64 + c];
          Bs[i][c] = pm[(size_t)(k*64+i)*b + tj*64 + c]; }
        __syncthreads();
        tile_gemm_step(acc, As, Bs, tx, ty);
      }
      #pragma unroll
      for (int u=0;u<4;++u)
        #pragma unroll
        for (int v=0;v<4;++v)
          linv[(size_t)(rb*64+ty*4+u)*MM + (m*2*nb+tj)*64 + tx*4+v] = -acc[u][v];
    }
    gbar(bar, gen);
  }

  // ---- phase 4: W = Linv @ tril(qL) (both GPs), then alpha = Linv @ qm ----
  for (int idx=bid; idx<2*528; idx+=GRIDN){
    int gp = idx/528, rem = idx%528;
    int bi=0; while ((bi+1)*(bi+2)/2 <= rem) ++bi;
    int bj = rem - bi*(bi+1)/2;
    const float* ql = gp ? qlg : qlf;
    float* w        = gp ? wg  : wf;
    float acc[4][4]={};
    for (int bk=bj; bk<=bi; ++bk){
      __syncthreads();
      for (int p=t;p<4096;p+=256){ int i=p>>6, c=p&63;
        As[i][c] = linv[(size_t)(bi*64+i)*MM + bk*64 + c];
        float qv = ql[(size_t)(bk*64+i)*MM + bj*64 + c];
        if (bk==bj && i<c) qv = 0.f;
        Bs[i][c] = qv; }
      __syncthreads();
      tile_gemm_step(acc, As, Bs, tx, ty);
    }
    #pragma unroll
    for (int u=0;u<4;++u)
      #pragma unroll
      for (int v=0;v<4;++v)
        w[(size_t)(bi*64+ty*4+u)*MM + bj*64 + tx*4+v] = acc[u][v];
  }
  {
    int gw = bid*4 + (t>>6), l = t&63;
    for (int job=gw; job<4096; job+=GRIDN*4){
      int gp = job>>11, r = job&2047;
      const float* qm = gp ? qmg : qmf;
      float s=0.f;
      for (int c=l; c<=r; c+=64) s += linv[(size_t)r*MM+c]*qm[c];
      #pragma unroll
      for (int off=32; off; off>>=1) s += __shfl_down(s, off, 64);
      if (l==0) (gp ? ag : af)[r] = s;
    }
  }
}

// ================= small kernels (pre/post) =================

// z fragments (B-operand, K=8 padded to 32) + |z|^2
__global__ __launch_bounds__(256) void zfrag_kernel(const float* __restrict__ z,
    short* __restrict__ zfh, short* __restrict__ zfl, float* __restrict__ zn2){
  int zr = blockIdx.x*256 + threadIdx.x;
  float v[DD]; float s = 0.f;
  #pragma unroll
  for (int d=0; d<DD; ++d){ v[d] = z[zr*DD + d]; s += v[d]*v[d]; }
  zn2[zr] = s;
  size_t base = (size_t)(zr >> 4)*512 + (zr & 15)*32;
  #pragma unroll
  for (int k=0; k<32; ++k){
    short h = 0, lo = 0;
    if (k < DD) bfsplit(v[k], h, lo);
    zfh[base + k] = h; zfl[base + k] = lo;
  }
}

// logdets + ||alpha||^2 (Lk diag lives in lkdiag)
__global__ __launch_bounds__(256) void red_small(const float* __restrict__ lkd,
    const float* __restrict__ qlf, const float* __restrict__ qlg,
    const float* __restrict__ af, const float* __restrict__ ag,
    float* __restrict__ scal){
  __shared__ float scratch[4];
  float ldk=0, ldf=0, ldg=0, a2f=0, a2g=0;
  for (int i=threadIdx.x;i<MM;i+=256){
    int kb = i>>6, r = i&63;
    ldk += __logf(lkd[kb*4096 + r*64 + r]);
    ldf += __logf(fabsf(qlf[(size_t)i*MM+i]));
    ldg += __logf(fabsf(qlg[(size_t)i*MM+i]));
    float v = af[i]; a2f += v*v;
    v = ag[i];       a2g += v*v;
  }
  float r;
  r = block_reduce(ldk, scratch); if (threadIdx.x==0) scal[0] = 2.f*r;
  r = block_reduce(ldf, scratch); if (threadIdx.x==0) scal[1] = 2.f*r;
  r = block_reduce(ldg, scratch); if (threadIdx.x==0) scal[2] = 2.f*r;
  r = block_reduce(a2f, scratch); if (threadIdx.x==0) scal[3] = r;
  r = block_reduce(a2g, scratch); if (threadIdx.x==0) scal[4] = r;
}

// ||W_f||^2, ||W_g||^2
__global__ __launch_bounds__(256) void redw_kernel(const float* __restrict__ wf,
    const float* __restrict__ wg, float* __restrict__ scal){
  __shared__ float scratch[4];
  size_t start  = (size_t)blockIdx.x*256 + threadIdx.x;
  size_t stride = (size_t)gridDim.x*256;
  float sf=0, sg=0;
  for (size_t p=start;p<(size_t)MM*MM;p+=stride){
    float v=wf[p]; sf += v*v;
    v=wg[p];       sg += v*v;
  }
  float r = block_reduce(sf, scratch);
  if (threadIdx.x==0) atomicAdd(&scal[5], r);
  r = block_reduce(sg, scratch);
  if (threadIdx.x==0) atomicAdd(&scal[6], r);
}

__global__ void kl_kernel(const float* __restrict__ scal, float* __restrict__ out){
  float klf = 0.5f*(scal[5] + scal[3] - (float)MM + scal[0] - scal[1]);
  float klg = 0.5f*(scal[6] + scal[4] - (float)MM + scal[0] - scal[2]);
  out[0] += klf + klg;
}

// fp32 row-major -> frag-order bf16 hi/lo (outer=row)
__global__ __launch_bounds__(256) void split_rowmajor(const float* __restrict__ src,
    short* __restrict__ dh, short* __restrict__ dl){
  int p = blockIdx.x*256 + threadIdx.x;
  int chunk = p >> 9, wi = p & 511;
  int mo = chunk >> 6, ko = chunk & 63;
  int row = mo*16 + (wi >> 5), col = ko*32 + (wi & 31);
  float v = src[(size_t)row*MM + col];
  short h, lo; bfsplit(v, h, lo);
  dh[p] = h; dl[p] = lo;
}

// fp32 (outer=col; W as B-operand) -> frag-order, via LDS transpose.
// ONE matrix per launch (keeps overlay reads/writes serialized).
__global__ __launch_bounds__(256) void split_transpose(const float* __restrict__ src,
    short* __restrict__ dh, short* __restrict__ dl){
  __shared__ float tile[32][33];
  int t = threadIdx.x;
  int mb = blockIdx.x, kb = blockIdx.y;
  #pragma unroll
  for (int k=0;k<4;++k){
    int idx = t + k*256;
    int lr = idx >> 5, lc = idx & 31;
    tile[lr][lc] = src[(size_t)(kb*32+lr)*MM + mb*32 + lc];
  }
  __syncthreads();
  #pragma unroll
  for (int e=0;e<4;++e){
    int p = t*4 + e;
    int c = p >> 9, wi = p & 511;
    int i = (wi >> 5) & 15, kk = wi & 31;
    float v = tile[kk][c*16 + i];
    short h, lo; bfsplit(v, h, lo);
    size_t gp = ((size_t)(mb*2 + c)*64 + kb)*512 + wi;
    dh[gp] = h; dl[gp] = lo;
  }
}

// T^T = Kfu @ Linv^T via split-bf16 MFMA (Kfu from in-register split-MFMA S)
__global__ __launch_bounds__(256, 2) void tt_mfma(
    const float* __restrict__ x, const float* __restrict__ zn2,
    const short* __restrict__ zfh, const short* __restrict__ zfl,
    const short* __restrict__ lvh, const short* __restrict__ lvl,
    short* __restrict__ tth, short* __restrict__ ttl){
  __shared__ __align__(16) short lAh[8192], lAl[8192], lBh[8192], lBl[8192];
  int t = threadIdx.x;
  int l = t & 63, w = t >> 6;
  int istrip = blockIdx.x, bj2 = blockIdx.y;
  int li = l & 15, q = l >> 4;
  int lofs = li*32 + q*8;
  int wn4 = (w>>1)*4, wm4 = (w&1)*4;

  short8 xh[2], xl[2];
  float xn2v[8];
  {
    float xn2t[2];
    #pragma unroll
    for (int tn=0; tn<2; ++tn){
      int n = istrip*128 + w*32 + tn*16 + li;
      const float4* xp = (const float4*)(x + (size_t)n*DD);
      float4 p0 = xp[0], p1 = xp[1];
      float v[8] = {p0.x,p0.y,p0.z,p0.w,p1.x,p1.y,p1.z,p1.w};
      float s = 0.f;
      #pragma unroll
      for (int d=0; d<8; ++d) s += v[d]*v[d];
      xn2t[tn] = s;
      short8 hh, ll;
      #pragma unroll
      for (int j=0; j<8; ++j){
        short h=0, lo=0;
        if (q==0) bfsplit(v[j], h, lo);
        hh[j]=h; ll[j]=lo;
      }
      xh[tn]=hh; xl[tn]=ll;
    }
    #pragma unroll
    for (int tn=0; tn<2; ++tn)
      #pragma unroll
      for (int r=0; r<4; ++r)
        xn2v[tn*4+r] = __shfl(xn2t[tn], q*4 + r, 64);
  }

  float4v acc[4][4];
  #pragma unroll
  for (int i=0;i<4;++i)
    #pragma unroll
    for (int j=0;j<4;++j) acc[i][j] = f4zero();

  int nkt = 2*bj2 + 2;
  for (int bk=0; bk<nkt; ++bk){
    __syncthreads();
    {
      short8 zh[4], zl[4];
      float zt2[4];
      #pragma unroll
      for (int tz=0; tz<4; ++tz){
        size_t zo = (size_t)(bk*4 + tz)*512 + lofs;
        zh[tz] = *(const short8*)(zfh + zo);
        zl[tz] = *(const short8*)(zfl + zo);
        zt2[tz] = zn2[bk*64 + tz*16 + li];
      }
      #pragma unroll
      for (int tn=0; tn<2; ++tn){
        #pragma unroll
        for (int tz=0; tz<4; ++tz){
          float4v s4 = mfma3(xh[tn], xl[tn], zh[tz], zl[tz], f4zero());
          #pragma unroll
          for (int r=0; r<4; ++r){
            float e = __expf(4.f*s4[r] - 2.f*(xn2v[tn*4+r] + zt2[tz]));
            short h, lo; bfsplit(e, h, lo);
            int pos = ((w*2+tn)*2 + (tz>>1))*512 + (q*4+r)*32 + (tz&1)*16 + li;
            lAh[pos] = h; lAl[pos] = lo;
          }
        }
      }
    }
    #pragma unroll
    for (int c4 = t; c4 < 1024; c4 += 256){
      int ch = c4 >> 6, wdi = c4 & 63;
      size_t g = ((size_t)(bj2*8 + (ch>>1))*64 + (size_t)(bk*2 + (ch&1)))*64 + wdi;
      ((uint4*)lBh)[c4] = ((const uint4*)lvh)[g];
      ((uint4*)lBl)[c4] = ((const uint4*)lvl)[g];
    }
    __syncthreads();
    #pragma unroll
    for (int s=0; s<2; ++s){
      short8 ah[4], al[4], bh[4], bl[4];
      #pragma unroll
      for (int tn=0; tn<4; ++tn){
        int off = ((wn4+tn)*2 + s)*512 + lofs;
        ah[tn] = *(const short8*)&lAh[off];
        al[tn] = *(const short8*)&lAl[off];
      }
      #pragma unroll
      for (int tm=0; tm<4; ++tm){
        int off = ((wm4+tm)*2 + s)*512 + lofs;
        bh[tm] = *(const short8*)&lBh[off];
        bl[tm] = *(const short8*)&lBl[off];
      }
      #pragma unroll
      for (int tn=0; tn<4; ++tn)
        #pragma unroll
        for (int tm=0; tm<4; ++tm)
          acc[tn][tm] = mfma3(ah[tn], al[tn], bh[tm], bl[tm], acc[tn][tm]);
    }
  }
  #pragma unroll
  for (int tn=0; tn<4; ++tn){
    int no_g = istrip*8 + wn4 + tn;
    #pragma unroll
    for (int tm=0; tm<4; ++tm){
      int mo_g = bj2*4 + (w&1)*2 + (tm>>1);
      size_t cb = ((size_t)no_g*64 + mo_g)*512;
      #pragma unroll
      for (int r=0; r<4; ++r){
        short h, lo; bfsplit(acc[tn][tm][r], h, lo);
        size_t pos = cb + (q*4+r)*32 + (tm&1)*16 + li;
        tth[pos] = h; ttl[pos] = lo;
      }
    }
  }
}

// per-row ||t||^2, t.alpha_f, t.alpha_g (frag-order tt)
__global__ __launch_bounds__(256) void lin_v2(const short* __restrict__ tth,
    const short* __restrict__ ttl, const float* __restrict__ af, const float* __restrict__ ag,
    float* __restrict__ t2, float* __restrict__ lf, float* __restrict__ lg){
  int t = threadIdx.x;
  int w = t >> 6, l = t & 63;
  int n = blockIdx.x*4 + w;
  int g = l >> 2, j = l & 3;
  float s2=0.f, sf=0.f, sg=0.f;
  #pragma unroll
  for (int it=0; it<4; ++it){
    int ck = g + it*16;
    size_t off = ((size_t)(n>>4)*64 + ck)*512 + (n&15)*32 + j*8;
    short8 h8 = *(const short8*)(tth + off);
    short8 l8 = *(const short8*)(ttl + off);
    int m0 = ck*32 + j*8;
    float4 a0 = *(const float4*)(af + m0), a1 = *(const float4*)(af + m0 + 4);
    float4 g0 = *(const float4*)(ag + m0), g1 = *(const float4*)(ag + m0 + 4);
    float av[8] = {a0.x,a0.y,a0.z,a0.w,a1.x,a1.y,a1.z,a1.w};
    float gv[8] = {g0.x,g0.y,g0.z,g0.w,g1.x,g1.y,g1.z,g1.w};
    #pragma unroll
    for (int e=0; e<8; ++e){
      float tv = bf2f(h8[e]) + bf2f(l8[e]);
      s2 += tv*tv; sf += tv*av[e]; sg += tv*gv[e];
    }
  }
  #pragma unroll
  for (int off=32; off; off>>=1){
    s2 += __shfl_down(s2, off, 64);
    sf += __shfl_down(sf, off, 64);
    sg += __shfl_down(sg, off, 64);
  }
  if (l==0){ t2[n] = s2; lf[n] = sf; lg[n] = sg; }
}

// U = T^T @ W (both GPs); accumulate row-sums of U^2
__global__ __launch_bounds__(256, 2) void quad_mfma(
    const short* __restrict__ tth, const short* __restrict__ ttl,
    const short* __restrict__ wfh, const short* __restrict__ wfl,
    const short* __restrict__ wgh, const short* __restrict__ wgl,
    float* __restrict__ vfq, float* __restrict__ vgq){
  __shared__ __align__(16) short lAh[8192], lAl[8192], lBh[8192], lBl[8192];
  int t = threadIdx.x, l = t & 63, w = t >> 6;
  int istrip = blockIdx.x, bj2 = blockIdx.y;
  const short* gbh = blockIdx.z ? wgh : wfh;
  const short* gbl = blockIdx.z ? wgl : wfl;
  float* vq = blockIdx.z ? vgq : vfq;
  int li = l & 15, q = l >> 4;
  int lofs = li*32 + q*8;
  int wn4 = (w>>1)*4, wm4 = (w&1)*4;

  float4v acc[4][4];
  #pragma unroll
  for (int i=0;i<4;++i)
    #pragma unroll
    for (int j=0;j<4;++j) acc[i][j] = f4zero();

  for (int bk=2*bj2; bk<32; ++bk){
    __syncthreads();
    #pragma unroll
    for (int c4 = t; c4 < 1024; c4 += 256){
      int ch = c4 >> 6, wdi = c4 & 63;
      size_t ga = ((size_t)(istrip*8 + (ch>>1))*64 + (size_t)(bk*2 + (ch&1)))*64 + wdi;
      ((uint4*)lAh)[c4] = ((const uint4*)tth)[ga];
      ((uint4*)lAl)[c4] = ((const uint4*)ttl)[ga];
      size_t gb = ((size_t)(bj2*8 + (ch>>1))*64 + (size_t)(bk*2 + (ch&1)))*64 + wdi;
      ((uint4*)lBh)[c4] = ((const uint4*)gbh)[gb];
      ((uint4*)lBl)[c4] = ((const uint4*)gbl)[gb];
    }
    __syncthreads();
    #pragma unroll
    for (int s=0; s<2; ++s){
      short8 ah[4], al[4], bh[4], bl[4];
      #pragma unroll
      for (int tn=0; tn<4; ++tn){
        int off = ((wn4+tn)*2 + s)*512 + lofs;
        ah[tn] = *(const short8*)&lAh[off];
        al[tn] = *(const short8*)&lAl[off];
      }
      #pragma unroll
      for (int tm=0; tm<4; ++tm){
        int off = ((wm4+tm)*2 + s)*512 + lofs;
        bh[tm] = *(const short8*)&lBh[off];
        bl[tm] = *(const short8*)&lBl[off];
      }
      #pragma unroll
      for (int tn=0; tn<4; ++tn)
        #pragma unroll
        for (int tm=0; tm<4; ++tm)
          acc[tn][tm] = mfma3(ah[tn], al[tn], bh[tm], bl[tm], acc[tn][tm]);
    }
  }
  float rs[16];
  #pragma unroll
  for (int tn=0; tn<4; ++tn)
    #pragma unroll
    for (int r=0; r<4; ++r){
      float s = 0.f;
      #pragma unroll
      for (int tm=0; tm<4; ++tm){ float v = acc[tn][tm][r]; s += v*v; }
      rs[tn*4+r] = s;
    }
  #pragma unroll
  for (int off=8; off; off>>=1)
    #pragma unroll
    for (int k=0; k<16; ++k) rs[k] += __shfl_down(rs[k], off, 16);
  if (li == 0){
    #pragma unroll
    for (int tn=0; tn<4; ++tn)
      #pragma unroll
      for (int r=0; r<4; ++r){
        int n = istrip*128 + (w>>1)*64 + tn*16 + q*4 + r;
        atomicAdd(&vq[n], rs[tn*4+r]);
      }
  }
}

// expectation term + reduce
__global__ __launch_bounds__(256) void final_kernel(const float* __restrict__ y,
    const float* __restrict__ t2, const float* __restrict__ lf, const float* __restrict__ lg,
    const float* __restrict__ vfq, const float* __restrict__ vgq, float* __restrict__ out){
  __shared__ float scratch[4];
  int i = blockIdx.x*256 + threadIdx.x;
  float mf = lf[i], mg = lg[i];
  float vf = 1.f + vfq[i] - t2[i];
  float vg = 1.f + vgq[i] - t2[i];
  float dy = y[i] - mf;
  float e = -HLOG2PI - 0.5f*mg - 0.5f*(dy*dy + vf)*__expf(-mg + 0.5f*vg);
  float r = block_reduce(e, scratch);
  if (threadIdx.x==0) atomicAdd(out, -r);
}

extern "C" void kernel_launch(void* const* d_in, const int* in_sizes, int n_in,
                              void* d_out, int out_size, void* d_ws, size_t ws_size,
                              hipStream_t stream){
  (void)in_sizes; (void)n_in; (void)out_size; (void)ws_size;
  const float* x   = (const float*)d_in[0];
  const float* y   = (const float*)d_in[1];
  const float* z   = (const float*)d_in[2];
  const float* qmf = (const float*)d_in[3];
  const float* qlf = (const float*)d_in[4];
  const float* qmg = (const float*)d_in[5];
  const float* qlg = (const float*)d_in[6];
  float* out = (float*)d_out;
  char* Bw = (char*)d_ws;

  // overlaid workspace (~185 MB, same extent as the round-2-passing layout):
  // region0 [0,16M):   kuu fp32 (Lk)    -> later lvh/lvl
  // region1 [16,32M):  linv fp32        -> later wfh/wfl
  // region2 [32,48M):  wf fp32          -> later wgh/wgl
  // region3 [48,64M):  wg fp32          -> later tth (48..112M), ttl (112..176M)
  // ptmp/lkdiag live at 64..68.5M (inside tth range, dead during factor_coop)
  float* kuu  = (float*)Bw;
  float* linv = (float*)(Bw + SZB);
  float* wf   = (float*)(Bw + 2*SZB);
  float* wg   = (float*)(Bw + 3*SZB);
  short* lvh  = (short*)Bw;
  short* lvl  = (short*)(Bw + SZB/2);
  short* wfh  = (short*)(Bw + SZB);
  short* wfl  = (short*)(Bw + SZB + SZB/2);
  short* wgh  = (short*)(Bw + 2*SZB);
  short* wgl  = (short*)(Bw + 2*SZB + SZB/2);
  short* tth  = (short*)(Bw + 3*SZB);
  short* ttl  = (short*)(Bw + 3*SZB + (size_t)NN*MM*2);
  float* ptmp   = (float*)(Bw + 4*SZB);                    // 4 MB
  float* lkdiag = (float*)(Bw + 4*SZB + (size_t)4194304);  // 512 KB
  float* sm   = (float*)(Bw + 3*SZB + (size_t)NN*MM*4);
  float* af = sm;          float* ag = af + MM;
  float* t2 = ag + MM;     float* lf = t2 + NN;   float* lg = lf + NN;
  float* vfq = lg + NN;    float* vgq = vfq + NN; float* scal = vgq + NN;
  int*   bar = (int*)(scal + 8);   // barrier counter, inside the zeroed region
  float* zn2 = scal + 16;
  short* zfh = (short*)(zn2 + MM);
  short* zfl = zfh + MM*32;

  hipMemsetAsync(out, 0, sizeof(float), stream);
  hipMemsetAsync(vfq, 0, (size_t)(2*NN + 16)*sizeof(float), stream);  // vfq,vgq,scal(+bar)
  hipMemsetAsync(wf,  0, 2*SZB, stream);    // W upper triangles must be 0
  hipMemsetAsync(linv,0, SZB,   stream);    // Linv upper must be 0

  zfrag_kernel<<<MM/256, 256, 0, stream>>>(z, zfh, zfl, zn2);

  factor_coop<<<GRIDN, 256, 0, stream>>>(z, qlf, qlg, qmf, qmg,
                                         kuu, linv, wf, wg, af, ag,
                                         ptmp, lkdiag, bar);

  red_small<<<1, 256, 0, stream>>>(lkdiag, qlf, qlg, af, ag, scal);
  redw_kernel<<<512, 256, 0, stream>>>(wf, wg, scal);
  kl_kernel<<<1, 1, 0, stream>>>(scal, out);

  split_rowmajor<<<MM*MM/256, 256, 0, stream>>>(linv, lvh, lvl);
  split_transpose<<<dim3(MM/32, MM/32), 256, 0, stream>>>(wf, wfh, wfl);
  split_transpose<<<dim3(MM/32, MM/32), 256, 0, stream>>>(wg, wgh, wgl);

  tt_mfma<<<dim3(NN/128, MM/128), 256, 0, stream>>>(x, zn2, zfh, zfl, lvh, lvl, tth, ttl);
  lin_v2<<<NN/4, 256, 0, stream>>>(tth, ttl, af, ag, t2, lf, lg);
  quad_mfma<<<dim3(NN/128, MM/128, 2), 256, 0, stream>>>(tth, ttl, wfh, wfl, wgh, wgl, vfq, vgq);
  final_kernel<<<NN/256, 256, 0, stream>>>(y, t2, lf, lg, vfq, vgq, out);
}

// Round 6
// 4742.968 us; speedup vs baseline: 2.7992x; 1.3679x over previous
//
#include <hip/hip_runtime.h>
#include <math.h>

// ChainedGP v6: v5 + (1) cheap grid barrier (relaxed-load polling, single
// arrive RMW, minimal fences — v5's atomicRMW-poll + double threadfence cost
// ~55us/barrier x 77), (2) diag factorization hidden under SYRK (lookahead),
// (3) float4 LDS staging/writeback in all factor phases.
#define NN 16384
#define MM 2048
#define DD 8
#define NB 32                     // MM/64
#define GRIDN 256                 // factor kernel grid (co-resident, 1/CU)
#define SZB ((size_t)16777216)    // 2048*2048*4 bytes

constexpr float HLOG2PI = 0.91893853320467274178f;

using short8  = __attribute__((ext_vector_type(8))) short;
using float4v = __attribute__((ext_vector_type(4))) float;

__device__ __forceinline__ float4v f4zero(){ float4v v; v[0]=0.f; v[1]=0.f; v[2]=0.f; v[3]=0.f; return v; }

__device__ __forceinline__ void bfsplit(float v, short& h, short& lo){
  unsigned b = __float_as_uint(v);
  h = (short)(b >> 16);
  float hf = __uint_as_float(b & 0xFFFF0000u);
  lo = (short)(__float_as_uint(v - hf) >> 16);
}
__device__ __forceinline__ float bf2f(short s){
  return __uint_as_float(((unsigned)(unsigned short)s) << 16);
}
__device__ __forceinline__ float4v mfma3(short8 ah, short8 al, short8 bh, short8 bl, float4v c){
  c = __builtin_amdgcn_mfma_f32_16x16x32_bf16(ah, bh, c, 0, 0, 0);
  c = __builtin_amdgcn_mfma_f32_16x16x32_bf16(ah, bl, c, 0, 0, 0);
  c = __builtin_amdgcn_mfma_f32_16x16x32_bf16(al, bh, c, 0, 0, 0);
  return c;
}

// grid barrier: 1 relaxed RMW arrival + relaxed-load polling of a separate
// release flag (different cacheline). Fences: 1 release before arrival,
// 1 acq_rel by releaser, 1 acquire after observation.
__device__ __forceinline__ void gbar(int* cnt, int* flag, int& gen){
  __syncthreads();
  if (threadIdx.x == 0){
    ++gen;
    __builtin_amdgcn_fence(__ATOMIC_RELEASE, "agent");
    int old = __hip_atomic_fetch_add(cnt, 1, __ATOMIC_RELAXED, __HIP_MEMORY_SCOPE_AGENT);
    if (old == gen*GRIDN - 1){
      __builtin_amdgcn_fence(__ATOMIC_ACQ_REL, "agent");
      __hip_atomic_store(flag, gen, __ATOMIC_RELAXED, __HIP_MEMORY_SCOPE_AGENT);
    } else {
      while (__hip_atomic_load(flag, __ATOMIC_RELAXED, __HIP_MEMORY_SCOPE_AGENT) < gen)
        __builtin_amdgcn_s_sleep(8);
    }
    __builtin_amdgcn_fence(__ATOMIC_ACQUIRE, "agent");
  }
  __syncthreads();
}

__device__ __forceinline__ float block_reduce(float v, float* scratch){
  int lane = threadIdx.x & 63;
  int w    = threadIdx.x >> 6;
  #pragma unroll
  for (int off=32; off; off>>=1) v += __shfl_down(v, off, 64);
  __syncthreads();
  if (lane==0) scratch[w] = v;
  __syncthreads();
  float r = 0.f;
  if (threadIdx.x < 4) r = scratch[threadIdx.x];
  if (w==0){ r += __shfl_down(r, 2, 64); r += __shfl_down(r, 1, 64); }
  return r;
}

// ---- 64x64 tile helpers (LDS row stride 68 floats = 16B-aligned rows) ----
__device__ __forceinline__ void stage64(float (*S)[68], const float* __restrict__ g, int ld, int t){
  #pragma unroll
  for (int p=t; p<1024; p+=256)
    *(float4*)&S[p>>4][(p&15)*4] = *(const float4*)&g[(size_t)(p>>4)*ld + (p&15)*4];
}
__device__ __forceinline__ void tile_gemm_step(float acc[4][4], const float (*As)[68], const float (*Bs)[68], int tx, int ty){
  for (int k=0;k<64;++k){
    float ar[4], bc4[4];
    #pragma unroll
    for (int u=0;u<4;++u){ ar[u]=As[ty*4+u][k]; bc4[u]=Bs[k][tx*4+u]; }
    #pragma unroll
    for (int u=0;u<4;++u)
      #pragma unroll
      for (int v=0;v<4;++v) acc[u][v] += ar[u]*bc4[v];
  }
}
__device__ __forceinline__ void tile_syrk_step(float acc[4][4], const float (*P)[68], const float (*Q)[68], int tx, int ty){
  for (int k=0;k<64;++k){
    float pr[4], qc[4];
    #pragma unroll
    for (int u=0;u<4;++u){ pr[u]=P[ty*4+u][k]; qc[u]=Q[tx*4+u][k]; }
    #pragma unroll
    for (int u=0;u<4;++u)
      #pragma unroll
      for (int v=0;v<4;++v) acc[u][v] += pr[u]*qc[v];
  }
}

// in-LDS Cholesky of a 64x64 tile (2 syncs/step); writes lkdiag[d]/sdg[d].
// Callers must __syncthreads() after filling A.
__device__ void factor64(float (*A)[68], float* __restrict__ lkd, float* __restrict__ sdg_, int d, int t){
  for (int j=0;j<64;++j){
    float ajj = A[j][j];                       // no writer this phase
    float piv = sqrtf(fmaxf(ajj, 1e-20f));
    float rp  = 1.f/piv;
    float val = 0.f;
    if (t>j && t<64){ val = A[t][j]*rp; A[t][j]=val; }   // own element only
    __syncthreads();
    if (t<64){
      if (t>j) for (int c=j+1;c<=t;++c) A[t][c] -= val*A[c][j];
      if (t==j){ A[j][j]=piv; sdg_[d*64+j]=rp; }
    }
    __syncthreads();
  }
  for (int p=t; p<4096; p+=256){ int i=p>>6, c=p&63;
    lkd[d*4096+p] = (c<=i)? A[i][c] : 0.f; }
}

// ================= fused factorization kernel (plain launch) =================
__global__ __launch_bounds__(256) void factor_coop(
    const float* __restrict__ z,
    const float* __restrict__ qlf, const float* __restrict__ qlg,
    const float* __restrict__ qmf, const float* __restrict__ qmg,
    float* __restrict__ kuu, float* __restrict__ linv,
    float* __restrict__ wf, float* __restrict__ wg,
    float* __restrict__ af, float* __restrict__ ag,
    float* __restrict__ ptmp, float* __restrict__ lkdiag,
    float* __restrict__ sdg, int* __restrict__ cnt, int* __restrict__ flag)
{
  __shared__ float As[64][68];
  __shared__ float Bs[64][68];
  __shared__ float sd[64];
  const int bid = blockIdx.x, t = threadIdx.x;
  const int tx = t & 15, ty = t >> 4;
  int gen = 0;

  // ---- phase 0: Kuu lower tiles (tile-wise); block 0 factors diag(0) ----
  if (bid == 0){
    // tile (0,0): z rows in As[.][0..7], compute in regs, factor in-LDS.
    for (int p=t; p<128; p+=256){ int i=p>>1, h=p&1;
      *(float4*)&As[i][h*4] = *(const float4*)&z[(size_t)i*DD + h*4]; }
    __syncthreads();
    float kv[4][4];
    #pragma unroll
    for (int u=0;u<4;++u)
      #pragma unroll
      for (int v=0;v<4;++v){
        float d2=0.f;
        #pragma unroll
        for (int d=0;d<8;++d){ float df=As[ty*4+u][d]-As[tx*4+v][d]; d2+=df*df; }
        kv[u][v] = __expf(-2.f*d2) + ((ty*4+u)==(tx*4+v) ? 1e-6f : 0.f);
      }
    __syncthreads();
    #pragma unroll
    for (int u=0;u<4;++u)
      #pragma unroll
      for (int v=0;v<4;++v) As[ty*4+u][tx*4+v] = kv[u][v];
    __syncthreads();
    factor64(As, lkdiag, sdg, 0, t);
  } else {
    for (int idx=bid; idx<528; idx+=GRIDN-1){
      int r=0; while ((r+1)*(r+2)/2 <= idx) ++r;
      int c = idx - r*(r+1)/2;
      __syncthreads();
      for (int p=t; p<128; p+=256){ int i=p>>1, h=p&1;
        *(float4*)&As[i][h*4] = *(const float4*)&z[(size_t)(r*64+i)*DD + h*4];
        *(float4*)&Bs[i][h*4] = *(const float4*)&z[(size_t)(c*64+i)*DD + h*4]; }
      __syncthreads();
      #pragma unroll
      for (int u=0;u<4;++u){
        float4 o;
        float* ov = (float*)&o;
        #pragma unroll
        for (int v=0;v<4;++v){
          float d2=0.f;
          #pragma unroll
          for (int d=0;d<8;++d){ float df=As[ty*4+u][d]-Bs[tx*4+v][d]; d2+=df*df; }
          float val = __expf(-2.f*d2);
          if (r*64+ty*4+u == c*64+tx*4+v) val += 1e-6f;
          ov[v] = val;
        }
        *(float4*)&kuu[(size_t)(r*64+ty*4+u)*MM + c*64 + tx*4] = o;
      }
    }
  }
  gbar(cnt, flag, gen);

  // ---- phase 1: blocked Cholesky with diag lookahead ----
  for (int kb=0; kb<31; ++kb){
    int R = MM - (kb+1)*64;
    int nact = (R + 255) >> 8;
    if (bid < nact){
      for (int p=t; p<1024; p+=256)
        *(float4*)&As[p>>4][(p&15)*4] = *(const float4*)&lkdiag[kb*4096 + p*4];
      if (t < 64) sd[t] = sdg[kb*64 + t];
      __syncthreads();
      int row = (kb+1)*64 + bid*256 + t;
      if (row < MM){
        float xr[64];
        float* ap = kuu + (size_t)row*MM + kb*64;
        #pragma unroll
        for (int c4=0; c4<16; ++c4) *(float4*)&xr[c4*4] = *(const float4*)&ap[c4*4];
        #pragma unroll
        for (int j=0; j<64; ++j){
          float xj = xr[j]*sd[j];
          xr[j] = xj;
          #pragma unroll
          for (int c=j+1; c<64; ++c) xr[c] -= xj*As[c][j];
        }
        #pragma unroll
        for (int c4=0; c4<16; ++c4) *(float4*)&ap[c4*4] = *(float4*)&xr[c4*4];
      }
    }
    gbar(cnt, flag, gen);

    int T = NB-1 - kb;
    int ntiles = T*(T+1)/2;
    if (bid == 0){
      // tile (kb+1,kb+1): SYRK + immediate diag factorization (lookahead)
      int bi = kb+1;
      stage64(As, kuu + (size_t)(bi*64)*MM + kb*64, MM, t);
      __syncthreads();
      float acc[4][4] = {};
      tile_syrk_step(acc, As, As, tx, ty);
      __syncthreads();
      #pragma unroll
      for (int u=0;u<4;++u)
        #pragma unroll
        for (int v=0;v<4;++v) Bs[ty*4+u][tx*4+v] = acc[u][v];
      __syncthreads();
      for (int p=t;p<1024;p+=256){
        int i=p>>4, c4=p&15;
        float4 kv = *(const float4*)&kuu[(size_t)(bi*64+i)*MM + bi*64 + c4*4];
        float4 bv = *(float4*)&Bs[i][c4*4];
        float4 o; o.x=kv.x-bv.x; o.y=kv.y-bv.y; o.z=kv.z-bv.z; o.w=kv.w-bv.w;
        *(float4*)&As[i][c4*4] = o;
      }
      __syncthreads();
      factor64(As, lkdiag, sdg, kb+1, t);
    } else {
      for (int idx=bid; idx<ntiles; idx+=GRIDN-1){
        int r=0; while ((r+1)*(r+2)/2 <= idx) ++r;
        int c = idx - r*(r+1)/2;
        int bi = kb+1+r, bc = kb+1+c;
        __syncthreads();
        stage64(As, kuu + (size_t)(bi*64)*MM + kb*64, MM, t);
        stage64(Bs, kuu + (size_t)(bc*64)*MM + kb*64, MM, t);
        __syncthreads();
        float acc[4][4] = {};
        tile_syrk_step(acc, As, Bs, tx, ty);
        #pragma unroll
        for (int u=0;u<4;++u){
          float4* dst = (float4*)&kuu[(size_t)(bi*64+ty*4+u)*MM + bc*64 + tx*4];
          float4 o = *dst;
          o.x-=acc[u][0]; o.y-=acc[u][1]; o.z-=acc[u][2]; o.w-=acc[u][3];
          *dst = o;
        }
      }
    }
    gbar(cnt, flag, gen);
  }

  // ---- phase 2: invert 64x64 diagonal blocks (from lkdiag) ----
  if (bid < NB){
    stage64(As, lkdiag + bid*4096, 64, t);
    __syncthreads();
    if (t < 64){
      for (int j=0;j<64;++j){
        float s = (j==t)?1.f:0.f;
        for (int k=t;k<j;++k) s -= As[j][k]*Bs[k][t];
        Bs[j][t] = (j>=t)? s/As[j][j] : 0.f;
      }
    }
    __syncthreads();
    for (int p=t;p<1024;p+=256){ int i=p>>4, c4=p&15;
      *(float4*)&linv[(size_t)(bid*64+i)*MM + bid*64 + c4*4] = *(float4*)&Bs[i][c4*4]; }
  }
  gbar(cnt, flag, gen);

  // ---- phase 3: recursive-doubling inversion: X21 = -X22 * A21 * X11 ----
  for (int s=0; s<5; ++s){
    int nb = 1<<s, mc = 16>>s, b = 64<<s;
    int tiles = mc*nb*nb;
    for (int idx=bid; idx<tiles; idx+=GRIDN){
      int m = idx/(nb*nb), r2 = idx%(nb*nb);
      int ti = r2/nb, tj = r2%nb;
      int rb = m*2*nb + nb + ti, cb0 = m*2*nb;
      float acc[4][4]={};
      for (int k=tj; k<nb; ++k){
        __syncthreads();
        stage64(As, kuu  + (size_t)(rb*64)*MM + (cb0+k)*64, MM, t);
        stage64(Bs, linv + (size_t)((cb0+k)*64)*MM + (cb0+tj)*64, MM, t);
        __syncthreads();
        tile_gemm_step(acc, As, Bs, tx, ty);
      }
      float* pm = ptmp + (size_t)m*b*b;
      #pragma unroll
      for (int u=0;u<4;++u)
        *(float4*)&pm[(size_t)(ti*64+ty*4+u)*b + tj*64 + tx*4] =
            make_float4(acc[u][0],acc[u][1],acc[u][2],acc[u][3]);
    }
    gbar(cnt, flag, gen);
    for (int idx=bid; idx<tiles; idx+=GRIDN){
      int m = idx/(nb*nb), r2 = idx%(nb*nb);
      int ti = r2/nb, tj = r2%nb;
      int rb = m*2*nb + nb + ti;
      const float* pm = ptmp + (size_t)m*b*b;
      float acc[4][4]={};
      for (int k=0; k<=ti; ++k){
        __syncthreads();
        stage64(As, linv + (size_t)(rb*64)*MM + (m*2*nb+nb+k)*64, MM, t);
        stage64(Bs, pm + (size_t)(k*64)*b + tj*64, b, t);
        __syncthreads();
        tile_gemm_step(acc, As, Bs, tx, ty);
      }
      #pragma unroll
      for (int u=0;u<4;++u)
        *(float4*)&linv[(size_t)(rb*64+ty*4+u)*MM + (m*2*nb+tj)*64 + tx*4] =
            make_float4(-acc[u][0],-acc[u][1],-acc[u][2],-acc[u][3]);
    }
    gbar(cnt, flag, gen);
  }

  // ---- phase 4: W = Linv @ tril(qL) (both GPs), then alpha = Linv @ qm ----
  for (int idx=bid; idx<2*528; idx+=GRIDN){
    int gp = idx/528, rem = idx%528;
    int bi=0; while ((bi+1)*(bi+2)/2 <= rem) ++bi;
    int bj = rem - bi*(bi+1)/2;
    const float* ql = gp ? qlg : qlf;
    float* w        = gp ? wg  : wf;
    float acc[4][4]={};
    for (int bk=bj; bk<=bi; ++bk){
      __syncthreads();
      stage64(As, linv + (size_t)(bi*64)*MM + bk*64, MM, t);
      stage64(Bs, ql   + (size_t)(bk*64)*MM + bj*64, MM, t);
      __syncthreads();
      if (bk==bj){
        for (int p=t;p<4096;p+=256){ int i=p>>6, c=p&63; if (i<c) Bs[i][c]=0.f; }
        __syncthreads();
      }
      tile_gemm_step(acc, As, Bs, tx, ty);
    }
    #pragma unroll
    for (int u=0;u<4;++u)
      *(float4*)&w[(size_t)(bi*64+ty*4+u)*MM + bj*64 + tx*4] =
          make_float4(acc[u][0],acc[u][1],acc[u][2],acc[u][3]);
  }
  {
    int gw = bid*4 + (t>>6), l = t&63;
    for (int job=gw; job<4096; job+=GRIDN*4){
      int gp = job>>11, r = job&2047;
      const float* qm = gp ? qmg : qmf;
      float s=0.f;
      for (int c=l; c<=r; c+=64) s += linv[(size_t)r*MM+c]*qm[c];
      #pragma unroll
      for (int off=32; off; off>>=1) s += __shfl_down(s, off, 64);
      if (l==0) (gp ? ag : af)[r] = s;
    }
  }
}

// ================= small kernels (pre/post) =================

__global__ __launch_bounds__(256) void zfrag_kernel(const float* __restrict__ z,
    short* __restrict__ zfh, short* __restrict__ zfl, float* __restrict__ zn2){
  int zr = blockIdx.x*256 + threadIdx.x;
  float v[DD]; float s = 0.f;
  #pragma unroll
  for (int d=0; d<DD; ++d){ v[d] = z[zr*DD + d]; s += v[d]*v[d]; }
  zn2[zr] = s;
  size_t base = (size_t)(zr >> 4)*512 + (zr & 15)*32;
  #pragma unroll
  for (int k=0; k<32; ++k){
    short h = 0, lo = 0;
    if (k < DD) bfsplit(v[k], h, lo);
    zfh[base + k] = h; zfl[base + k] = lo;
  }
}

__global__ __launch_bounds__(256) void red_small(const float* __restrict__ lkd,
    const float* __restrict__ qlf, const float* __restrict__ qlg,
    const float* __restrict__ af, const float* __restrict__ ag,
    float* __restrict__ scal){
  __shared__ float scratch[4];
  float ldk=0, ldf=0, ldg=0, a2f=0, a2g=0;
  for (int i=threadIdx.x;i<MM;i+=256){
    int kb = i>>6, r = i&63;
    ldk += __logf(lkd[kb*4096 + r*64 + r]);
    ldf += __logf(fabsf(qlf[(size_t)i*MM+i]));
    ldg += __logf(fabsf(qlg[(size_t)i*MM+i]));
    float v = af[i]; a2f += v*v;
    v = ag[i];       a2g += v*v;
  }
  float r;
  r = block_reduce(ldk, scratch); if (threadIdx.x==0) scal[0] = 2.f*r;
  r = block_reduce(ldf, scratch); if (threadIdx.x==0) scal[1] = 2.f*r;
  r = block_reduce(ldg, scratch); if (threadIdx.x==0) scal[2] = 2.f*r;
  r = block_reduce(a2f, scratch); if (threadIdx.x==0) scal[3] = r;
  r = block_reduce(a2g, scratch); if (threadIdx.x==0) scal[4] = r;
}

__global__ __launch_bounds__(256) void redw_kernel(const float* __restrict__ wf,
    const float* __restrict__ wg, float* __restrict__ scal){
  __shared__ float scratch[4];
  size_t start  = (size_t)blockIdx.x*256 + threadIdx.x;
  size_t stride = (size_t)gridDim.x*256;
  float sf=0, sg=0;
  for (size_t p=start;p<(size_t)MM*MM;p+=stride){
    float v=wf[p]; sf += v*v;
    v=wg[p];       sg += v*v;
  }
  float r = block_reduce(sf, scratch);
  if (threadIdx.x==0) atomicAdd(&scal[5], r);
  r = block_reduce(sg, scratch);
  if (threadIdx.x==0) atomicAdd(&scal[6], r);
}

__global__ void kl_kernel(const float* __restrict__ scal, float* __restrict__ out){
  float klf = 0.5f*(scal[5] + scal[3] - (float)MM + scal[0] - scal[1]);
  float klg = 0.5f*(scal[6] + scal[4] - (float)MM + scal[0] - scal[2]);
  out[0] += klf + klg;
}

__global__ __launch_bounds__(256) void split_rowmajor(const float* __restrict__ src,
    short* __restrict__ dh, short* __restrict__ dl){
  int p = blockIdx.x*256 + threadIdx.x;
  int chunk = p >> 9, wi = p & 511;
  int mo = chunk >> 6, ko = chunk & 63;
  int row = mo*16 + (wi >> 5), col = ko*32 + (wi & 31);
  float v = src[(size_t)row*MM + col];
  short h, lo; bfsplit(v, h, lo);
  dh[p] = h; dl[p] = lo;
}

__global__ __launch_bounds__(256) void split_transpose(const float* __restrict__ src,
    short* __restrict__ dh, short* __restrict__ dl){
  __shared__ float tile[32][33];
  int t = threadIdx.x;
  int mb = blockIdx.x, kb = blockIdx.y;
  #pragma unroll
  for (int k=0;k<4;++k){
    int idx = t + k*256;
    int lr = idx >> 5, lc = idx & 31;
    tile[lr][lc] = src[(size_t)(kb*32+lr)*MM + mb*32 + lc];
  }
  __syncthreads();
  #pragma unroll
  for (int e=0;e<4;++e){
    int p = t*4 + e;
    int c = p >> 9, wi = p & 511;
    int i = (wi >> 5) & 15, kk = wi & 31;
    float v = tile[kk][c*16 + i];
    short h, lo; bfsplit(v, h, lo);
    size_t gp = ((size_t)(mb*2 + c)*64 + kb)*512 + wi;
    dh[gp] = h; dl[gp] = lo;
  }
}

__global__ __launch_bounds__(256, 2) void tt_mfma(
    const float* __restrict__ x, const float* __restrict__ zn2,
    const short* __restrict__ zfh, const short* __restrict__ zfl,
    const short* __restrict__ lvh, const short* __restrict__ lvl,
    short* __restrict__ tth, short* __restrict__ ttl){
  __shared__ __align__(16) short lAh[8192], lAl[8192], lBh[8192], lBl[8192];
  int t = threadIdx.x;
  int l = t & 63, w = t >> 6;
  int istrip = blockIdx.x, bj2 = blockIdx.y;
  int li = l & 15, q = l >> 4;
  int lofs = li*32 + q*8;
  int wn4 = (w>>1)*4, wm4 = (w&1)*4;

  short8 xh[2], xl[2];
  float xn2v[8];
  {
    float xn2t[2];
    #pragma unroll
    for (int tn=0; tn<2; ++tn){
      int n = istrip*128 + w*32 + tn*16 + li;
      const float4* xp = (const float4*)(x + (size_t)n*DD);
      float4 p0 = xp[0], p1 = xp[1];
      float v[8] = {p0.x,p0.y,p0.z,p0.w,p1.x,p1.y,p1.z,p1.w};
      float s = 0.f;
      #pragma unroll
      for (int d=0; d<8; ++d) s += v[d]*v[d];
      xn2t[tn] = s;
      short8 hh, ll;
      #pragma unroll
      for (int j=0; j<8; ++j){
        short h=0, lo=0;
        if (q==0) bfsplit(v[j], h, lo);
        hh[j]=h; ll[j]=lo;
      }
      xh[tn]=hh; xl[tn]=ll;
    }
    #pragma unroll
    for (int tn=0; tn<2; ++tn)
      #pragma unroll
      for (int r=0; r<4; ++r)
        xn2v[tn*4+r] = __shfl(xn2t[tn], q*4 + r, 64);
  }

  float4v acc[4][4];
  #pragma unroll
  for (int i=0;i<4;++i)
    #pragma unroll
    for (int j=0;j<4;++j) acc[i][j] = f4zero();

  int nkt = 2*bj2 + 2;
  for (int bk=0; bk<nkt; ++bk){
    __syncthreads();
    {
      short8 zh[4], zl[4];
      float zt2[4];
      #pragma unroll
      for (int tz=0; tz<4; ++tz){
        size_t zo = (size_t)(bk*4 + tz)*512 + lofs;
        zh[tz] = *(const short8*)(zfh + zo);
        zl[tz] = *(const short8*)(zfl + zo);
        zt2[tz] = zn2[bk*64 + tz*16 + li];
      }
      #pragma unroll
      for (int tn=0; tn<2; ++tn){
        #pragma unroll
        for (int tz=0; tz<4; ++tz){
          float4v s4 = mfma3(xh[tn], xl[tn], zh[tz], zl[tz], f4zero());
          #pragma unroll
          for (int r=0; r<4; ++r){
            float e = __expf(4.f*s4[r] - 2.f*(xn2v[tn*4+r] + zt2[tz]));
            short h, lo; bfsplit(e, h, lo);
            int pos = ((w*2+tn)*2 + (tz>>1))*512 + (q*4+r)*32 + (tz&1)*16 + li;
            lAh[pos] = h; lAl[pos] = lo;
          }
        }
      }
    }
    #pragma unroll
    for (int c4 = t; c4 < 1024; c4 += 256){
      int ch = c4 >> 6, wdi = c4 & 63;
      size_t g = ((size_t)(bj2*8 + (ch>>1))*64 + (size_t)(bk*2 + (ch&1)))*64 + wdi;
      ((uint4*)lBh)[c4] = ((const uint4*)lvh)[g];
      ((uint4*)lBl)[c4] = ((const uint4*)lvl)[g];
    }
    __syncthreads();
    #pragma unroll
    for (int s=0; s<2; ++s){
      short8 ah[4], al[4], bh[4], bl[4];
      #pragma unroll
      for (int tn=0; tn<4; ++tn){
        int off = ((wn4+tn)*2 + s)*512 + lofs;
        ah[tn] = *(const short8*)&lAh[off];
        al[tn] = *(const short8*)&lAl[off];
      }
      #pragma unroll
      for (int tm=0; tm<4; ++tm){
        int off = ((wm4+tm)*2 + s)*512 + lofs;
        bh[tm] = *(const short8*)&lBh[off];
        bl[tm] = *(const short8*)&lBl[off];
      }
      #pragma unroll
      for (int tn=0; tn<4; ++tn)
        #pragma unroll
        for (int tm=0; tm<4; ++tm)
          acc[tn][tm] = mfma3(ah[tn], al[tn], bh[tm], bl[tm], acc[tn][tm]);
    }
  }
  #pragma unroll
  for (int tn=0; tn<4; ++tn){
    int no_g = istrip*8 + wn4 + tn;
    #pragma unroll
    for (int tm=0; tm<4; ++tm){
      int mo_g = bj2*4 + (w&1)*2 + (tm>>1);
      size_t cb = ((size_t)no_g*64 + mo_g)*512;
      #pragma unroll
      for (int r=0; r<4; ++r){
        short h, lo; bfsplit(acc[tn][tm][r], h, lo);
        size_t pos = cb + (q*4+r)*32 + (tm&1)*16 + li;
        tth[pos] = h; ttl[pos] = lo;
      }
    }
  }
}

__global__ __launch_bounds__(256) void lin_v2(const short* __restrict__ tth,
    const short* __restrict__ ttl, const float* __restrict__ af, const float* __restrict__ ag,
    float* __restrict__ t2, float* __restrict__ lf, float* __restrict__ lg){
  int t = threadIdx.x;
  int w = t >> 6, l = t & 63;
  int n = blockIdx.x*4 + w;
  int g = l >> 2, j = l & 3;
  float s2=0.f, sf=0.f, sg=0.f;
  #pragma unroll
  for (int it=0; it<4; ++it){
    int ck = g + it*16;
    size_t off = ((size_t)(n>>4)*64 + ck)*512 + (n&15)*32 + j*8;
    short8 h8 = *(const short8*)(tth + off);
    short8 l8 = *(const short8*)(ttl + off);
    int m0 = ck*32 + j*8;
    float4 a0 = *(const float4*)(af + m0), a1 = *(const float4*)(af + m0 + 4);
    float4 g0 = *(const float4*)(ag + m0), g1 = *(const float4*)(ag + m0 + 4);
    float av[8] = {a0.x,a0.y,a0.z,a0.w,a1.x,a1.y,a1.z,a1.w};
    float gv[8] = {g0.x,g0.y,g0.z,g0.w,g1.x,g1.y,g1.z,g1.w};
    #pragma unroll
    for (int e=0; e<8; ++e){
      float tv = bf2f(h8[e]) + bf2f(l8[e]);
      s2 += tv*tv; sf += tv*av[e]; sg += tv*gv[e];
    }
  }
  #pragma unroll
  for (int off=32; off; off>>=1){
    s2 += __shfl_down(s2, off, 64);
    sf += __shfl_down(sf, off, 64);
    sg += __shfl_down(sg, off, 64);
  }
  if (l==0){ t2[n] = s2; lf[n] = sf; lg[n] = sg; }
}

__global__ __launch_bounds__(256, 2) void quad_mfma(
    const short* __restrict__ tth, const short* __restrict__ ttl,
    const short* __restrict__ wfh, const short* __restrict__ wfl,
    const short* __restrict__ wgh, const short* __restrict__ wgl,
    float* __restrict__ vfq, float* __restrict__ vgq){
  __shared__ __align__(16) short lAh[8192], lAl[8192], lBh[8192], lBl[8192];
  int t = threadIdx.x, l = t & 63, w = t >> 6;
  int istrip = blockIdx.x, bj2 = blockIdx.y;
  const short* gbh = blockIdx.z ? wgh : wfh;
  const short* gbl = blockIdx.z ? wgl : wfl;
  float* vq = blockIdx.z ? vgq : vfq;
  int li = l & 15, q = l >> 4;
  int lofs = li*32 + q*8;
  int wn4 = (w>>1)*4, wm4 = (w&1)*4;

  float4v acc[4][4];
  #pragma unroll
  for (int i=0;i<4;++i)
    #pragma unroll
    for (int j=0;j<4;++j) acc[i][j] = f4zero();

  for (int bk=2*bj2; bk<32; ++bk){
    __syncthreads();
    #pragma unroll
    for (int c4 = t; c4 < 1024; c4 += 256){
      int ch = c4 >> 6, wdi = c4 & 63;
      size_t ga = ((size_t)(istrip*8 + (ch>>1))*64 + (size_t)(bk*2 + (ch&1)))*64 + wdi;
      ((uint4*)lAh)[c4] = ((const uint4*)tth)[ga];
      ((uint4*)lAl)[c4] = ((const uint4*)ttl)[ga];
      size_t gb = ((size_t)(bj2*8 + (ch>>1))*64 + (size_t)(bk*2 + (ch&1)))*64 + wdi;
      ((uint4*)lBh)[c4] = ((const uint4*)gbh)[gb];
      ((uint4*)lBl)[c4] = ((const uint4*)gbl)[gb];
    }
    __syncthreads();
    #pragma unroll
    for (int s=0; s<2; ++s){
      short8 ah[4], al[4], bh[4], bl[4];
      #pragma unroll
      for (int tn=0; tn<4; ++tn){
        int off = ((wn4+tn)*2 + s)*512 + lofs;
        ah[tn] = *(const short8*)&lAh[off];
        al[tn] = *(const short8*)&lAl[off];
      }
      #pragma unroll
      for (int tm=0; tm<4; ++tm){
        int off = ((wm4+tm)*2 + s)*512 + lofs;
        bh[tm] = *(const short8*)&lBh[off];
        bl[tm] = *(const short8*)&lBl[off];
      }
      #pragma unroll
      for (int tn=0; tn<4; ++tn)
        #pragma unroll
        for (int tm=0; tm<4; ++tm)
          acc[tn][tm] = mfma3(ah[tn], al[tn], bh[tm], bl[tm], acc[tn][tm]);
    }
  }
  float rs[16];
  #pragma unroll
  for (int tn=0; tn<4; ++tn)
    #pragma unroll
    for (int r=0; r<4; ++r){
      float s = 0.f;
      #pragma unroll
      for (int tm=0; tm<4; ++tm){ float v = acc[tn][tm][r]; s += v*v; }
      rs[tn*4+r] = s;
    }
  #pragma unroll
  for (int off=8; off; off>>=1)
    #pragma unroll
    for (int k=0; k<16; ++k) rs[k] += __shfl_down(rs[k], off, 16);
  if (li == 0){
    #pragma unroll
    for (int tn=0; tn<4; ++tn)
      #pragma unroll
      for (int r=0; r<4; ++r){
        int n = istrip*128 + (w>>1)*64 + tn*16 + q*4 + r;
        atomicAdd(&vq[n], rs[tn*4+r]);
      }
  }
}

__global__ __launch_bounds__(256) void final_kernel(const float* __restrict__ y,
    const float* __restrict__ t2, const float* __restrict__ lf, const float* __restrict__ lg,
    const float* __restrict__ vfq, const float* __restrict__ vgq, float* __restrict__ out){
  __shared__ float scratch[4];
  int i = blockIdx.x*256 + threadIdx.x;
  float mf = lf[i], mg = lg[i];
  float vf = 1.f + vfq[i] - t2[i];
  float vg = 1.f + vgq[i] - t2[i];
  float dy = y[i] - mf;
  float e = -HLOG2PI - 0.5f*mg - 0.5f*(dy*dy + vf)*__expf(-mg + 0.5f*vg);
  float r = block_reduce(e, scratch);
  if (threadIdx.x==0) atomicAdd(out, -r);
}

extern "C" void kernel_launch(void* const* d_in, const int* in_sizes, int n_in,
                              void* d_out, int out_size, void* d_ws, size_t ws_size,
                              hipStream_t stream){
  (void)in_sizes; (void)n_in; (void)out_size; (void)ws_size;
  const float* x   = (const float*)d_in[0];
  const float* y   = (const float*)d_in[1];
  const float* z   = (const float*)d_in[2];
  const float* qmf = (const float*)d_in[3];
  const float* qlf = (const float*)d_in[4];
  const float* qmg = (const float*)d_in[5];
  const float* qlg = (const float*)d_in[6];
  float* out = (float*)d_out;
  char* Bw = (char*)d_ws;

  float* kuu  = (float*)Bw;
  float* linv = (float*)(Bw + SZB);
  float* wf   = (float*)(Bw + 2*SZB);
  float* wg   = (float*)(Bw + 3*SZB);
  short* lvh  = (short*)Bw;
  short* lvl  = (short*)(Bw + SZB/2);
  short* wfh  = (short*)(Bw + SZB);
  short* wfl  = (short*)(Bw + SZB + SZB/2);
  short* wgh  = (short*)(Bw + 2*SZB);
  short* wgl  = (short*)(Bw + 2*SZB + SZB/2);
  short* tth  = (short*)(Bw + 3*SZB);
  short* ttl  = (short*)(Bw + 3*SZB + (size_t)NN*MM*2);
  float* ptmp   = (float*)(Bw + 4*SZB);                    // 4 MB (dead tt region)
  float* lkdiag = (float*)(Bw + 4*SZB + (size_t)4194304);  // 512 KB
  float* sdg    = (float*)(Bw + 4*SZB + (size_t)4194304 + (size_t)524288); // 8 KB
  float* sm   = (float*)(Bw + 3*SZB + (size_t)NN*MM*4);
  float* af = sm;          float* ag = af + MM;
  float* t2 = ag + MM;     float* lf = t2 + NN;   float* lg = lf + NN;
  float* vfq = lg + NN;    float* vgq = vfq + NN; float* scal = vgq + NN;
  int*   cnt  = (int*)(scal + 8);    // barrier arrive counter
  int*   flag = (int*)(scal + 40);   // barrier release flag (separate line)
  float* zn2 = scal + 48;
  short* zfh = (short*)(zn2 + MM);
  short* zfl = zfh + MM*32;

  hipMemsetAsync(out, 0, sizeof(float), stream);
  hipMemsetAsync(vfq, 0, (size_t)(2*NN + 48)*sizeof(float), stream);  // vfq,vgq,scal,cnt,flag
  hipMemsetAsync(wf,  0, 2*SZB, stream);    // W upper triangles must be 0
  hipMemsetAsync(linv,0, SZB,   stream);    // Linv upper must be 0

  zfrag_kernel<<<MM/256, 256, 0, stream>>>(z, zfh, zfl, zn2);

  factor_coop<<<GRIDN, 256, 0, stream>>>(z, qlf, qlg, qmf, qmg,
                                         kuu, linv, wf, wg, af, ag,
                                         ptmp, lkdiag, sdg, cnt, flag);

  red_small<<<1, 256, 0, stream>>>(lkdiag, qlf, qlg, af, ag, scal);
  redw_kernel<<<512, 256, 0, stream>>>(wf, wg, scal);
  kl_kernel<<<1, 1, 0, stream>>>(scal, out);

  split_rowmajor<<<MM*MM/256, 256, 0, stream>>>(linv, lvh, lvl);
  split_transpose<<<dim3(MM/32, MM/32), 256, 0, stream>>>(wf, wfh, wfl);
  split_transpose<<<dim3(MM/32, MM/32), 256, 0, stream>>>(wg, wgh, wgl);

  tt_mfma<<<dim3(NN/128, MM/128), 256, 0, stream>>>(x, zn2, zfh, zfl, lvh, lvl, tth, ttl);
  lin_v2<<<NN/4, 256, 0, stream>>>(tth, ttl, af, ag, t2, lf, lg);
  quad_mfma<<<dim3(NN/128, MM/128, 2), 256, 0, stream>>>(tth, ttl, wfh, wfl, wgh, wgl, vfq, vgq);
  final_kernel<<<NN/256, 256, 0, stream>>>(y, t2, lf, lg, vfq, vgq, out);
}